// Round 8
// baseline (314.751 us; speedup 1.0000x reference)
//
#include <hip/hip_runtime.h>
#include <hip/hip_bf16.h>

#define NN 50000
#define NE 1600000
#define DD 128
#define KC 16

// Buckets of 32 dst-rows: bucket = dst >> 5
#define NB 1563           // ceil(50000/32)
#define NBP (NB + 1)
#define CHUNK 6144        // edges per binsort block
#define NCHUNK 261        // ceil(NE/CHUNK)
#define EPT 12            // CHUNK / 512 edges per thread
#define MAXB 1536         // bucket capacity (avg 1024, sigma ~32)

typedef __attribute__((ext_vector_type(8))) short s8v;   // 8 bf16 = 4 VGPRs
typedef __attribute__((ext_vector_type(4))) float f4v;   // 4 fp32 acc
typedef __attribute__((ext_vector_type(2))) float f2v;   // fp32 pair -> v_pk_fma_f32

__device__ __forceinline__ f2v up2(unsigned u) {
    f2v r;
    r.x = __uint_as_float(u << 16);
    r.y = __uint_as_float(u & 0xFFFF0000u);
    return r;
}

// ---------------- chunk-local counting sort by bucket (single-writer windows) ----------------

__global__ __launch_bounds__(512) void k_binsort(const int* __restrict__ dst,
                                                 const int* __restrict__ src,
                                                 const float* __restrict__ w,
                                                 int2* __restrict__ staging2,
                                                 unsigned short* __restrict__ offs) {
    __shared__ int cnt[NB];
    __shared__ int s[512];
    int t = threadIdx.x;
    int c = blockIdx.x;
    size_t cbase = (size_t)c * CHUNK;
    for (int i = t; i < NB; i += 512) cnt[i] = 0;
    __syncthreads();

    int dreg[EPT], sreg[EPT]; float wreg[EPT];
    #pragma unroll
    for (int j = 0; j < EPT; j++) {
        size_t e = cbase + j * 512 + t;
        bool ok = e < NE;
        size_t ee = ok ? e : (NE - 1);
        dreg[j] = dst[ee]; sreg[j] = src[ee]; wreg[j] = w[ee];
        if (!ok) dreg[j] = -1;
        if (ok) atomicAdd(&cnt[dreg[j] >> 5], 1);
    }
    __syncthreads();

    int v[4]; int sum = 0;
    #pragma unroll
    for (int j = 0; j < 4; j++) { int i = t * 4 + j; v[j] = (i < NB) ? cnt[i] : 0; sum += v[j]; }
    s[t] = sum; __syncthreads();
    for (int off = 1; off < 512; off <<= 1) {
        int u = (t >= off) ? s[t - off] : 0;
        __syncthreads();
        s[t] += u;
        __syncthreads();
    }
    int run = (t == 0) ? 0 : s[t - 1];
    #pragma unroll
    for (int j = 0; j < 4; j++) {
        int i = t * 4 + j;
        if (i < NB) { offs[(size_t)c * NBP + i] = (unsigned short)run; cnt[i] = run; run += v[j]; }
    }
    if (t == 511) offs[(size_t)c * NBP + NB] = (unsigned short)s[511];
    __syncthreads();

    #pragma unroll
    for (int j = 0; j < EPT; j++) {
        if (dreg[j] >= 0) {
            int b = dreg[j] >> 5;
            int li = atomicAdd(&cnt[b], 1);
            staging2[cbase + li] = make_int2(((dreg[j] & 31) << 16) | sreg[j],
                                            __float_as_int(wreg[j]));
        }
    }
}

// ---------------- per-bucket merge + row sort -> flat row-sorted staging + rowbeg/rowend ----------------

__global__ __launch_bounds__(256) void k_rowsort(const int2* __restrict__ staging2,
                                                 const unsigned short* __restrict__ offs,
                                                 int2* __restrict__ staging,
                                                 int* __restrict__ rowbeg,
                                                 int* __restrict__ rowend) {
    __shared__ int2 ebuf[MAXB];
    __shared__ int2 ebuf2[MAXB];
    __shared__ int segoff[NCHUNK];
    __shared__ int cstart[NCHUNK];
    __shared__ int s2[256];
    __shared__ int rcnt[32];
    __shared__ int rowoff[33];
    int b = blockIdx.x, t = threadIdx.x;

    for (int c = t; c < NCHUNK; c += 256) {
        int o0 = offs[(size_t)c * NBP + b];
        int o1 = offs[(size_t)c * NBP + b + 1];
        cstart[c] = o0;
        segoff[c] = o1 - o0;
    }
    __syncthreads();
    int a0 = (2 * t < NCHUNK) ? segoff[2 * t] : 0;
    int a1 = (2 * t + 1 < NCHUNK) ? segoff[2 * t + 1] : 0;
    s2[t] = a0 + a1; __syncthreads();
    for (int off = 1; off < 256; off <<= 1) {
        int u = (t >= off) ? s2[t - off] : 0;
        __syncthreads();
        s2[t] += u;
        __syncthreads();
    }
    int base0 = (t == 0) ? 0 : s2[t - 1];
    int total = s2[255];
    __syncthreads();
    if (2 * t < NCHUNK) segoff[2 * t] = base0;
    if (2 * t + 1 < NCHUNK) segoff[2 * t + 1] = base0 + a0;
    __syncthreads();

    int cnt = total; if (cnt > MAXB) cnt = MAXB;

    for (int c = t; c < NCHUNK; c += 256) {
        int so = segoff[c], st = cstart[c];
        int o1 = offs[(size_t)c * NBP + b + 1];
        const int2* sp = staging2 + (size_t)c * CHUNK + st;
        int len = o1 - st;
        for (int j = 0; j < len; j++) {
            int p = so + j;
            if (p < MAXB) ebuf[p] = sp[j];
        }
    }
    __syncthreads();

    if (t < 32) rcnt[t] = 0;
    __syncthreads();
    for (int i = t; i < cnt; i += 256) atomicAdd(&rcnt[(unsigned)ebuf[i].x >> 16], 1);
    __syncthreads();
    if (t < 32) {
        int v = rcnt[t];
        int p = v;
        #pragma unroll
        for (int off = 1; off < 32; off <<= 1) {
            int u = __shfl_up(p, off, 64);
            if (t >= off) p += u;
        }
        rowoff[t] = p - v;
        if (t == 31) rowoff[32] = p;
        rcnt[t] = p - v;
    }
    __syncthreads();
    for (int i = t; i < cnt; i += 256) {
        int2 rec = ebuf[i];
        int p = atomicAdd(&rcnt[(unsigned)rec.x >> 16], 1);
        ebuf2[p] = rec;
    }
    __syncthreads();

    int2* outp = staging + (size_t)b * MAXB;
    for (int i = t; i < cnt; i += 256) outp[i] = ebuf2[i];
    if (t < 8 && cnt + t < MAXB) outp[cnt + t] = make_int2(0, 0);  // zero pads for tail reads
    if (t < 32) {
        int g = b * 32 + t;
        if (g < NN) {
            rowbeg[g] = b * MAXB + rowoff[t];
            rowend[g] = b * MAXB + rowoff[t + 1];
        }
    }
}

// ---------------- W preconvert: fp32 [128][128] -> bf16 frags ----------------

__global__ __launch_bounds__(256) void k_wprep(const float* __restrict__ W,
                                               s8v* __restrict__ Wf) {
    int g = blockIdx.x * 256 + threadIdx.x;   // 2048 threads
    int l = g & 63;
    int kcnt = g >> 6;                         // 0..31
    int kc = kcnt >> 3, nt = kcnt & 7;
    int n = nt * 16 + (l & 15);
    int kb = kc * 32 + (l >> 4) * 8;
    union { s8v v; __hip_bfloat162 h2[4]; } u;
    #pragma unroll
    for (int q = 0; q < 4; q++) {
        float lo = W[(size_t)(kb + 2 * q) * 128 + n];
        float hi = W[(size_t)(kb + 2 * q + 1) * 128 + n];
        u.h2[q] = __float22bfloat162_rn(make_float2(lo, hi));
    }
    Wf[(size_t)kcnt * 64 + l] = u.v;
}

// ---------------- MFMA GEMM: T = bf16( X @ W + bias ), input fp32 or bf16 ----------------

__device__ __forceinline__ s8v load_afrag(const float* p) {
    union { s8v v; __hip_bfloat162 h2[4]; } a;
    float4 f0 = *(const float4*)p;
    float4 f1 = *(const float4*)(p + 4);
    a.h2[0] = __float22bfloat162_rn(make_float2(f0.x, f0.y));
    a.h2[1] = __float22bfloat162_rn(make_float2(f0.z, f0.w));
    a.h2[2] = __float22bfloat162_rn(make_float2(f1.x, f1.y));
    a.h2[3] = __float22bfloat162_rn(make_float2(f1.z, f1.w));
    return a.v;
}
__device__ __forceinline__ s8v load_afrag(const __hip_bfloat16* p) {
    return *(const s8v*)p;
}

template <typename TI>
__global__ __launch_bounds__(256) void k_gemm_mfma(const TI* __restrict__ X,
                                                   const s8v* __restrict__ Wf,
                                                   const float* __restrict__ bias,
                                                   __hip_bfloat16* __restrict__ Out,
                                                   int nrows) {
    int wave = blockIdx.x * 4 + (threadIdx.x >> 6);
    int lane = threadIdx.x & 63;
    int m0 = wave * 32;
    if (m0 >= nrows) return;
    int col = lane & 15;
    int quad = lane >> 4;

    f4v acc[2][8];
    #pragma unroll
    for (int mt = 0; mt < 2; mt++)
        #pragma unroll
        for (int nt = 0; nt < 8; nt++) acc[mt][nt] = (f4v){0.f, 0.f, 0.f, 0.f};

    int row0 = m0 + col;
    int row1 = m0 + 16 + col;
    if (row0 >= nrows) row0 = nrows - 1;
    if (row1 >= nrows) row1 = nrows - 1;
    const TI* xr0 = X + (size_t)row0 * 128 + quad * 8;
    const TI* xr1 = X + (size_t)row1 * 128 + quad * 8;

    #pragma unroll 1
    for (int kc = 0; kc < 4; kc++) {
        s8v a0 = load_afrag(xr0 + kc * 32);
        s8v a1 = load_afrag(xr1 + kc * 32);
        #pragma unroll
        for (int nt = 0; nt < 8; nt++) {
            s8v b = Wf[(size_t)(kc * 8 + nt) * 64 + lane];
            acc[0][nt] = __builtin_amdgcn_mfma_f32_16x16x32_bf16(a0, b, acc[0][nt], 0, 0, 0);
            acc[1][nt] = __builtin_amdgcn_mfma_f32_16x16x32_bf16(a1, b, acc[1][nt], 0, 0, 0);
        }
    }

    float bb[8];
    #pragma unroll
    for (int nt = 0; nt < 8; nt++) bb[nt] = bias[nt * 16 + col];

    #pragma unroll
    for (int mt = 0; mt < 2; mt++) {
        #pragma unroll
        for (int r = 0; r < 4; r++) {
            int row = m0 + mt * 16 + quad * 4 + r;
            if (row < nrows) {
                __hip_bfloat16* orow = Out + (size_t)row * 128 + col;
                #pragma unroll
                for (int nt = 0; nt < 8; nt++) {
                    orow[nt * 16] = __float2bfloat16(acc[mt][nt][r] + bb[nt]);
                }
            }
        }
    }
}

// ---------------- streaming SPMM, one wave per row ----------------
// lane = 16*q + fk : quarter q handles edge (o+q), feature group fk (features 8fk..8fk+7).
// ASSIGN=0: Hout(bf16) = selu(skip*t + agg).  ASSIGN=1: out = softmax(h@Wa+ba).

template <int ASSIGN>
__global__ __launch_bounds__(256) void k_spmm(const __hip_bfloat16* __restrict__ T,
                                              const int2* __restrict__ staging,
                                              const int* __restrict__ rowbeg,
                                              const int* __restrict__ rowend,
                                              const float* __restrict__ skip,
                                              __hip_bfloat16* __restrict__ Hout,
                                              const float* __restrict__ Wa,
                                              const float* __restrict__ ba,
                                              float* __restrict__ aout) {
    int g = (blockIdx.x * 256 + threadIdx.x) >> 6;
    if (g >= NN) return;
    int lane = threadIdx.x & 63;
    int q = lane >> 4;
    int fk = lane & 15;
    const int4* Tv4 = (const int4*)T;   // row = 16 int4 (256 B)

    float sk[8];
    *(float4*)&sk[0] = *(const float4*)(skip + fk * 8);
    *(float4*)&sk[4] = *(const float4*)(skip + fk * 8 + 4);

    float wreg[32];  // ASSIGN: Wa[8fk+j][4q+c]
    float bav[4];
    if (ASSIGN) {
        #pragma unroll
        for (int j = 0; j < 8; j++)
            *(float4*)&wreg[j * 4] = *(const float4*)(Wa + (size_t)(8 * fk + j) * KC + 4 * q);
        #pragma unroll
        for (int c = 0; c < 4; c++) bav[c] = ba[4 * q + c];
    }

    int o = rowbeg[g];
    int oe = rowend[g];
    f2v a01 = (f2v){0.f, 0.f}, a23 = (f2v){0.f, 0.f};
    f2v a45 = (f2v){0.f, 0.f}, a67 = (f2v){0.f, 0.f};

    for (; o + 8 <= oe; o += 8) {
        int2 r0 = staging[o + q];
        int2 r1 = staging[o + 4 + q];
        int4 t0 = Tv4[(size_t)(r0.x & 0xFFFF) * 16 + fk];
        int4 t1 = Tv4[(size_t)(r1.x & 0xFFFF) * 16 + fk];
        float w0 = __int_as_float(r0.y), w1 = __int_as_float(r1.y);
        a01 += w0 * up2(t0.x); a23 += w0 * up2(t0.y);
        a45 += w0 * up2(t0.z); a67 += w0 * up2(t0.w);
        a01 += w1 * up2(t1.x); a23 += w1 * up2(t1.y);
        a45 += w1 * up2(t1.z); a67 += w1 * up2(t1.w);
    }
    for (; o < oe; o += 4) {
        int i0 = o + q;
        int2 r0 = staging[i0];
        bool ok = i0 < oe;
        int sidx = ok ? (r0.x & 0xFFFF) : 0;
        float w0 = ok ? __int_as_float(r0.y) : 0.f;
        int4 t0 = Tv4[(size_t)sidx * 16 + fk];
        a01 += w0 * up2(t0.x); a23 += w0 * up2(t0.y);
        a45 += w0 * up2(t0.z); a67 += w0 * up2(t0.w);
    }

    // combine quarters
    float acc[8];
    acc[0] = a01.x; acc[1] = a01.y; acc[2] = a23.x; acc[3] = a23.y;
    acc[4] = a45.x; acc[5] = a45.y; acc[6] = a67.x; acc[7] = a67.y;
    #pragma unroll
    for (int j = 0; j < 8; j++) {
        acc[j] += __shfl_xor(acc[j], 16, 64);
        acc[j] += __shfl_xor(acc[j], 32, 64);
    }

    // self + skip + SELU
    const float scale = 1.0507009873554805f, alpha = 1.6732632423543772f;
    int4 ts = Tv4[(size_t)g * 16 + fk];
    f2v s01 = up2(ts.x), s23 = up2(ts.y), s45 = up2(ts.z), s67 = up2(ts.w);
    float v[8];
    v[0] = sk[0] * s01.x + acc[0]; v[1] = sk[1] * s01.y + acc[1];
    v[2] = sk[2] * s23.x + acc[2]; v[3] = sk[3] * s23.y + acc[3];
    v[4] = sk[4] * s45.x + acc[4]; v[5] = sk[5] * s45.y + acc[5];
    v[6] = sk[6] * s67.x + acc[6]; v[7] = sk[7] * s67.y + acc[7];
    #pragma unroll
    for (int j = 0; j < 8; j++)
        v[j] = scale * (v[j] > 0.f ? v[j] : alpha * (__expf(v[j]) - 1.f));

    if (!ASSIGN) {
        if (q == 0) {
            union { int4 i4; __hip_bfloat162 h2[4]; } pk;
            #pragma unroll
            for (int j = 0; j < 4; j++)
                pk.h2[j] = __float22bfloat162_rn(make_float2(v[2 * j], v[2 * j + 1]));
            *(int4*)(Hout + (size_t)g * 128 + fk * 8) = pk.i4;
        }
    } else {
        float p4[4] = {0.f, 0.f, 0.f, 0.f};
        #pragma unroll
        for (int j = 0; j < 8; j++)
            #pragma unroll
            for (int c = 0; c < 4; c++) p4[c] += v[j] * wreg[j * 4 + c];
        #pragma unroll
        for (int off = 1; off <= 8; off <<= 1)
            #pragma unroll
            for (int c = 0; c < 4; c++) p4[c] += __shfl_xor(p4[c], off, 64);
        #pragma unroll
        for (int c = 0; c < 4; c++) p4[c] += bav[c];
        float m = fmaxf(fmaxf(p4[0], p4[1]), fmaxf(p4[2], p4[3]));
        m = fmaxf(m, __shfl_xor(m, 16, 64));
        m = fmaxf(m, __shfl_xor(m, 32, 64));
        float e0 = __expf(p4[0] - m), e1 = __expf(p4[1] - m);
        float e2 = __expf(p4[2] - m), e3 = __expf(p4[3] - m);
        float s = e0 + e1 + e2 + e3;
        s += __shfl_xor(s, 16, 64);
        s += __shfl_xor(s, 32, 64);
        if (fk < 4) {
            float ev = e0;
            ev = (fk == 1) ? e1 : ev;
            ev = (fk == 2) ? e2 : ev;
            ev = (fk == 3) ? e3 : ev;
            aout[(size_t)g * KC + 4 * q + fk] = ev / s;
        }
    }
}

// ---------------- launch ----------------

extern "C" void kernel_launch(void* const* d_in, const int* in_sizes, int n_in,
                              void* d_out, int out_size, void* d_ws, size_t ws_size,
                              hipStream_t stream) {
    const float* x     = (const float*)d_in[0];
    const int*   eidx  = (const int*)d_in[1];
    const float* ew    = (const float*)d_in[2];
    const float* W1    = (const float*)d_in[3];
    const float* b1    = (const float*)d_in[4];
    const float* skip1 = (const float*)d_in[5];
    const float* W2    = (const float*)d_in[6];
    const float* b2    = (const float*)d_in[7];
    const float* skip2 = (const float*)d_in[8];
    const float* Wa    = (const float*)d_in[9];
    const float* ba    = (const float*)d_in[10];
    float* out = (float*)d_out;

    const int* dst = eidx;
    const int* src = eidx + NE;

    char* ws = (char*)d_ws;
    size_t off = 0;
    __hip_bfloat16* T = (__hip_bfloat16*)(ws + off);  off += (size_t)NN * DD * 2;   // 12.8 MB
    __hip_bfloat16* Hb = (__hip_bfloat16*)(ws + off); off += (size_t)NN * DD * 2;   // 12.8 MB
    // staging2 (chunk-sorted, dead after k_rowsort) aliases Hb (first written in spmm1)
    int2* staging2 = (int2*)Hb;                       // needs 12.23 MB <= 12.8 MB
    int2* staging = (int2*)(ws + off);                off += ((size_t)NB * MAXB + 16) * 8;  // 19.2 MB
    unsigned short* offs = (unsigned short*)(ws + off); off += (size_t)NCHUNK * NBP * 2;    // 816 KB
    int* rowbeg = (int*)(ws + off);                   off += (size_t)NN * 4;
    int* rowend = (int*)(ws + off);                   off += (size_t)NN * 4;
    s8v* Wf1 = (s8v*)(ws + off);                      off += 2048 * 16;             // 32 KB
    s8v* Wf2 = (s8v*)(ws + off);                      off += 2048 * 16;             // 32 KB

    k_binsort<<<NCHUNK, 512, 0, stream>>>(dst, src, ew, staging2, offs);
    k_rowsort<<<NB, 256, 0, stream>>>(staging2, offs, staging, rowbeg, rowend);

    k_wprep<<<8, 256, 0, stream>>>(W1, Wf1);
    k_wprep<<<8, 256, 0, stream>>>(W2, Wf2);

    int gemm_grid = (NN / 128) + 1;    // 391 blocks x 4 waves x 32 rows
    int spmm_grid = (NN + 3) / 4;      // 12500 blocks, 1 wave per row
    // layer 1
    k_gemm_mfma<float><<<gemm_grid, 256, 0, stream>>>(x, Wf1, b1, T, NN);
    k_spmm<0><<<spmm_grid, 256, 0, stream>>>(T, staging, rowbeg, rowend, skip1, Hb,
                                             nullptr, nullptr, nullptr);
    // layer 2
    k_gemm_mfma<__hip_bfloat16><<<gemm_grid, 256, 0, stream>>>(Hb, Wf2, b2, T, NN);
    k_spmm<1><<<spmm_grid, 256, 0, stream>>>(T, staging, rowbeg, rowend, skip2, nullptr,
                                             Wa, ba, out);
}

// Round 9
// 269.649 us; speedup vs baseline: 1.1673x; 1.1673x over previous
//
#include <hip/hip_runtime.h>
#include <hip/hip_bf16.h>
#include <hip/hip_fp16.h>

#define NN 50000
#define NE 1600000
#define DD 128
#define KC 16

// Buckets of 32 dst-rows: bucket = dst >> 5
#define NB 1563           // ceil(50000/32)
#define NBP (NB + 1)
#define CHUNK 6144        // edges per binsort block
#define NCHUNK 261        // ceil(NE/CHUNK)
#define BT 1024           // binsort block threads
#define EPT 6             // CHUNK / BT edges per thread
#define MAXB 1536         // bucket capacity (avg 1024, sigma ~32)

typedef __attribute__((ext_vector_type(8))) short s8v;   // 8 bf16 = 4 VGPRs
typedef __attribute__((ext_vector_type(4))) float f4v;   // 4 fp32 acc
typedef __attribute__((ext_vector_type(2))) float f2v;   // fp32 pair -> v_pk_fma_f32

__device__ __forceinline__ f2v up2(unsigned u) {
    f2v r;
    r.x = __uint_as_float(u << 16);
    r.y = __uint_as_float(u & 0xFFFF0000u);
    return r;
}
__device__ __forceinline__ float wof(unsigned rec) {
    return __half2float(__ushort_as_half((unsigned short)(rec >> 16)));
}

// ---------------- chunk-local counting sort by bucket (single-writer windows) ----------------
// staging2 record (8 B): .x = (row_in_bucket << 16) | src, .y = bits(f32 w)

__global__ __launch_bounds__(BT) void k_binsort(const int* __restrict__ dst,
                                                const int* __restrict__ src,
                                                const float* __restrict__ w,
                                                int2* __restrict__ staging2,
                                                unsigned short* __restrict__ offs) {
    __shared__ int cnt[NB];
    __shared__ int s[BT];
    int t = threadIdx.x;
    int c = blockIdx.x;
    size_t cbase = (size_t)c * CHUNK;
    for (int i = t; i < NB; i += BT) cnt[i] = 0;
    __syncthreads();

    int dreg[EPT], sreg[EPT]; float wreg[EPT];
    #pragma unroll
    for (int j = 0; j < EPT; j++) {
        size_t e = cbase + j * BT + t;
        bool ok = e < NE;
        size_t ee = ok ? e : (NE - 1);
        dreg[j] = dst[ee]; sreg[j] = src[ee]; wreg[j] = w[ee];
        if (!ok) dreg[j] = -1;
        if (ok) atomicAdd(&cnt[dreg[j] >> 5], 1);
    }
    __syncthreads();

    // exclusive scan of cnt[0..NB)
    int v[2]; int sum = 0;
    #pragma unroll
    for (int j = 0; j < 2; j++) { int i = t * 2 + j; v[j] = (i < NB) ? cnt[i] : 0; sum += v[j]; }
    s[t] = sum; __syncthreads();
    for (int off = 1; off < BT; off <<= 1) {
        int u = (t >= off) ? s[t - off] : 0;
        __syncthreads();
        s[t] += u;
        __syncthreads();
    }
    int run = (t == 0) ? 0 : s[t - 1];
    #pragma unroll
    for (int j = 0; j < 2; j++) {
        int i = t * 2 + j;
        if (i < NB) { offs[(size_t)c * NBP + i] = (unsigned short)run; cnt[i] = run; run += v[j]; }
    }
    if (t == BT - 1) offs[(size_t)c * NBP + NB] = (unsigned short)s[BT - 1];
    __syncthreads();

    #pragma unroll
    for (int j = 0; j < EPT; j++) {
        if (dreg[j] >= 0) {
            int b = dreg[j] >> 5;
            int li = atomicAdd(&cnt[b], 1);
            staging2[cbase + li] = make_int2(((dreg[j] & 31) << 16) | sreg[j],
                                            __float_as_int(wreg[j]));
        }
    }
}

// ---------------- per-bucket merge + row sort -> packed 4-B row-sorted staging ----------------
// staging4 record: src | (f16bits(w) << 16).  rowptr[b*33 + r]: LOCAL row offsets.

__global__ __launch_bounds__(256) void k_rowsort(const int2* __restrict__ staging2,
                                                 const unsigned short* __restrict__ offs,
                                                 unsigned* __restrict__ staging4,
                                                 int* __restrict__ rowptr) {
    __shared__ int2 ebuf[MAXB];
    __shared__ unsigned srec[MAXB];
    __shared__ int segoff[NCHUNK + 1];
    __shared__ int cstart[NCHUNK];
    __shared__ int s2[256];
    __shared__ int rcnt[32];
    __shared__ int rowoff[33];
    int b = blockIdx.x, t = threadIdx.x;

    for (int c = t; c < NCHUNK; c += 256) {
        int o0 = offs[(size_t)c * NBP + b];
        int o1 = offs[(size_t)c * NBP + b + 1];
        cstart[c] = o0;
        segoff[c] = o1 - o0;   // temporarily length
    }
    __syncthreads();
    int a0 = (2 * t < NCHUNK) ? segoff[2 * t] : 0;
    int a1 = (2 * t + 1 < NCHUNK) ? segoff[2 * t + 1] : 0;
    s2[t] = a0 + a1; __syncthreads();
    for (int off = 1; off < 256; off <<= 1) {
        int u = (t >= off) ? s2[t - off] : 0;
        __syncthreads();
        s2[t] += u;
        __syncthreads();
    }
    int base0 = (t == 0) ? 0 : s2[t - 1];
    int total = s2[255];
    __syncthreads();
    if (2 * t < NCHUNK) segoff[2 * t] = base0;
    if (2 * t + 1 < NCHUNK) segoff[2 * t + 1] = base0 + a0;
    if (t == 0) segoff[NCHUNK] = total;
    __syncthreads();

    int cnt = total; if (cnt > MAXB) cnt = MAXB;

    // parallel gather: record i -> binary search its chunk
    for (int i = t; i < cnt; i += 256) {
        int lo = 0, hi = NCHUNK;
        while (hi - lo > 1) {
            int mid = (lo + hi) >> 1;
            if (segoff[mid] <= i) lo = mid; else hi = mid;
        }
        ebuf[i] = staging2[(size_t)lo * CHUNK + cstart[lo] + (i - segoff[lo])];
    }
    __syncthreads();

    if (t < 32) rcnt[t] = 0;
    __syncthreads();
    for (int i = t; i < cnt; i += 256) atomicAdd(&rcnt[(unsigned)ebuf[i].x >> 16], 1);
    __syncthreads();
    if (t < 32) {
        int v = rcnt[t];
        int p = v;
        #pragma unroll
        for (int off = 1; off < 32; off <<= 1) {
            int u = __shfl_up(p, off, 64);
            if (t >= off) p += u;
        }
        rowoff[t] = p - v;
        if (t == 31) rowoff[32] = p;
        rcnt[t] = p - v;   // cursor
    }
    __syncthreads();
    for (int i = t; i < cnt; i += 256) {
        int2 rec = ebuf[i];
        int p = atomicAdd(&rcnt[(unsigned)rec.x >> 16], 1);
        unsigned hb = __half_as_ushort(__float2half_rn(__int_as_float(rec.y)));
        srec[p] = ((unsigned)rec.x & 0xFFFFu) | (hb << 16);
    }
    __syncthreads();

    unsigned* outp = staging4 + (size_t)b * MAXB;
    for (int i = t; i < cnt; i += 256) outp[i] = srec[i];
    if (t < 8 && cnt + t < MAXB) outp[cnt + t] = 0u;   // zero pads (src=0, w=0)
    if (t < 33) rowptr[b * 33 + t] = rowoff[t];
}

// ---------------- W preconvert: fp32 [128][128] -> bf16 frags ----------------

__global__ __launch_bounds__(256) void k_wprep(const float* __restrict__ W,
                                               s8v* __restrict__ Wf) {
    int g = blockIdx.x * 256 + threadIdx.x;   // 2048 threads
    int l = g & 63;
    int kcnt = g >> 6;                         // 0..31
    int kc = kcnt >> 3, nt = kcnt & 7;
    int n = nt * 16 + (l & 15);
    int kb = kc * 32 + (l >> 4) * 8;
    union { s8v v; __hip_bfloat162 h2[4]; } u;
    #pragma unroll
    for (int q = 0; q < 4; q++) {
        float lo = W[(size_t)(kb + 2 * q) * 128 + n];
        float hi = W[(size_t)(kb + 2 * q + 1) * 128 + n];
        u.h2[q] = __float22bfloat162_rn(make_float2(lo, hi));
    }
    Wf[(size_t)kcnt * 64 + l] = u.v;
}

// ---------------- MFMA GEMM: T = bf16( X @ W + bias ), input fp32 or bf16 ----------------

__device__ __forceinline__ s8v load_afrag(const float* p) {
    union { s8v v; __hip_bfloat162 h2[4]; } a;
    float4 f0 = *(const float4*)p;
    float4 f1 = *(const float4*)(p + 4);
    a.h2[0] = __float22bfloat162_rn(make_float2(f0.x, f0.y));
    a.h2[1] = __float22bfloat162_rn(make_float2(f0.z, f0.w));
    a.h2[2] = __float22bfloat162_rn(make_float2(f1.x, f1.y));
    a.h2[3] = __float22bfloat162_rn(make_float2(f1.z, f1.w));
    return a.v;
}
__device__ __forceinline__ s8v load_afrag(const __hip_bfloat16* p) {
    return *(const s8v*)p;
}

template <typename TI>
__global__ __launch_bounds__(256) void k_gemm_mfma(const TI* __restrict__ X,
                                                   const s8v* __restrict__ Wf,
                                                   const float* __restrict__ bias,
                                                   __hip_bfloat16* __restrict__ Out,
                                                   int nrows) {
    int wave = blockIdx.x * 4 + (threadIdx.x >> 6);
    int lane = threadIdx.x & 63;
    int m0 = wave * 32;
    if (m0 >= nrows) return;
    int col = lane & 15;
    int quad = lane >> 4;

    f4v acc[2][8];
    #pragma unroll
    for (int mt = 0; mt < 2; mt++)
        #pragma unroll
        for (int nt = 0; nt < 8; nt++) acc[mt][nt] = (f4v){0.f, 0.f, 0.f, 0.f};

    int row0 = m0 + col;
    int row1 = m0 + 16 + col;
    if (row0 >= nrows) row0 = nrows - 1;
    if (row1 >= nrows) row1 = nrows - 1;
    const TI* xr0 = X + (size_t)row0 * 128 + quad * 8;
    const TI* xr1 = X + (size_t)row1 * 128 + quad * 8;

    #pragma unroll 1
    for (int kc = 0; kc < 4; kc++) {
        s8v a0 = load_afrag(xr0 + kc * 32);
        s8v a1 = load_afrag(xr1 + kc * 32);
        #pragma unroll
        for (int nt = 0; nt < 8; nt++) {
            s8v b = Wf[(size_t)(kc * 8 + nt) * 64 + lane];
            acc[0][nt] = __builtin_amdgcn_mfma_f32_16x16x32_bf16(a0, b, acc[0][nt], 0, 0, 0);
            acc[1][nt] = __builtin_amdgcn_mfma_f32_16x16x32_bf16(a1, b, acc[1][nt], 0, 0, 0);
        }
    }

    float bb[8];
    #pragma unroll
    for (int nt = 0; nt < 8; nt++) bb[nt] = bias[nt * 16 + col];

    #pragma unroll
    for (int mt = 0; mt < 2; mt++) {
        #pragma unroll
        for (int r = 0; r < 4; r++) {
            int row = m0 + mt * 16 + quad * 4 + r;
            if (row < nrows) {
                __hip_bfloat16* orow = Out + (size_t)row * 128 + col;
                #pragma unroll
                for (int nt = 0; nt < 8; nt++) {
                    orow[nt * 16] = __float2bfloat16(acc[mt][nt][r] + bb[nt]);
                }
            }
        }
    }
}

// ---------------- SPMM: bucket per block, pre-sorted 4-B records in LDS ----------------
// lane = 16*q + fk : quarter q handles edge (o+q), feature group fk (8 features).
// ASSIGN=0: Hout(bf16) = selu(skip*t + agg).  ASSIGN=1: out = softmax(h@Wa+ba).

template <int ASSIGN>
__global__ __launch_bounds__(256) void k_spmm(const __hip_bfloat16* __restrict__ T,
                                              const unsigned* __restrict__ staging4,
                                              const int* __restrict__ rowptr,
                                              const float* __restrict__ skip,
                                              __hip_bfloat16* __restrict__ Hout,
                                              const float* __restrict__ Wa,
                                              const float* __restrict__ ba,
                                              float* __restrict__ aout) {
    __shared__ __align__(16) unsigned erec[MAXB + 16];
    __shared__ int rowoff[33];
    int b = blockIdx.x;
    int tid = threadIdx.x;

    if (tid < 33) rowoff[tid] = rowptr[b * 33 + tid];
    __syncthreads();
    int cnt = rowoff[32];
    int nv4 = (cnt + 11) >> 2;   // records + 8 pads, in uint4s
    const uint4* sp4 = (const uint4*)(staging4 + (size_t)b * MAXB);
    for (int i = tid; i < nv4; i += 256) ((uint4*)erec)[i] = sp4[i];
    __syncthreads();

    int wv = tid >> 6, lane = tid & 63;
    int q = lane >> 4;
    int fk = lane & 15;
    const int4* Tv4 = (const int4*)T;   // row = 16 int4 (256 B)

    float sk[8];
    *(float4*)&sk[0] = *(const float4*)(skip + fk * 8);
    *(float4*)&sk[4] = *(const float4*)(skip + fk * 8 + 4);

    float wreg[32];  // ASSIGN: Wa[8fk+j][4q+c]
    float bav[4];
    if (ASSIGN) {
        #pragma unroll
        for (int j = 0; j < 8; j++)
            *(float4*)&wreg[j * 4] = *(const float4*)(Wa + (size_t)(8 * fk + j) * KC + 4 * q);
        #pragma unroll
        for (int c = 0; c < 4; c++) bav[c] = ba[4 * q + c];
    }

    int nrows = NN - b * 32;
    if (nrows > 32) nrows = 32;
    const float scale = 1.0507009873554805f, alpha = 1.6732632423543772f;

    for (int r = wv; r < nrows; r += 4) {
        int g = b * 32 + r;
        int o = rowoff[r], oe = rowoff[r + 1];
        f2v a01 = (f2v){0.f, 0.f}, a23 = (f2v){0.f, 0.f};
        f2v a45 = (f2v){0.f, 0.f}, a67 = (f2v){0.f, 0.f};

        for (; o + 8 <= oe; o += 8) {
            unsigned c0 = erec[o + q];
            unsigned c1 = erec[o + 4 + q];
            int4 t0 = Tv4[(size_t)(c0 & 0xFFFFu) * 16 + fk];
            int4 t1 = Tv4[(size_t)(c1 & 0xFFFFu) * 16 + fk];
            float w0 = wof(c0), w1 = wof(c1);
            a01 += w0 * up2(t0.x); a23 += w0 * up2(t0.y);
            a45 += w0 * up2(t0.z); a67 += w0 * up2(t0.w);
            a01 += w1 * up2(t1.x); a23 += w1 * up2(t1.y);
            a45 += w1 * up2(t1.z); a67 += w1 * up2(t1.w);
        }
        for (; o < oe; o += 4) {           // masked tail (pads keep reads safe)
            int i0 = o + q;
            unsigned c0 = erec[i0];
            int4 t0 = Tv4[(size_t)(c0 & 0xFFFFu) * 16 + fk];
            float w0 = (i0 < oe) ? wof(c0) : 0.f;
            a01 += w0 * up2(t0.x); a23 += w0 * up2(t0.y);
            a45 += w0 * up2(t0.z); a67 += w0 * up2(t0.w);
        }

        float acc[8];
        acc[0] = a01.x; acc[1] = a01.y; acc[2] = a23.x; acc[3] = a23.y;
        acc[4] = a45.x; acc[5] = a45.y; acc[6] = a67.x; acc[7] = a67.y;
        #pragma unroll
        for (int j = 0; j < 8; j++) {
            acc[j] += __shfl_xor(acc[j], 16, 64);
            acc[j] += __shfl_xor(acc[j], 32, 64);
        }

        int4 ts = Tv4[(size_t)g * 16 + fk];
        f2v s01 = up2(ts.x), s23 = up2(ts.y), s45 = up2(ts.z), s67 = up2(ts.w);
        float v[8];
        v[0] = sk[0] * s01.x + acc[0]; v[1] = sk[1] * s01.y + acc[1];
        v[2] = sk[2] * s23.x + acc[2]; v[3] = sk[3] * s23.y + acc[3];
        v[4] = sk[4] * s45.x + acc[4]; v[5] = sk[5] * s45.y + acc[5];
        v[6] = sk[6] * s67.x + acc[6]; v[7] = sk[7] * s67.y + acc[7];
        #pragma unroll
        for (int j = 0; j < 8; j++)
            v[j] = scale * (v[j] > 0.f ? v[j] : alpha * (__expf(v[j]) - 1.f));

        if (!ASSIGN) {
            if (q == 0) {
                union { int4 i4; __hip_bfloat162 h2[4]; } pk;
                #pragma unroll
                for (int j = 0; j < 4; j++)
                    pk.h2[j] = __float22bfloat162_rn(make_float2(v[2 * j], v[2 * j + 1]));
                *(int4*)(Hout + (size_t)g * 128 + fk * 8) = pk.i4;
            }
        } else {
            float p4[4] = {0.f, 0.f, 0.f, 0.f};
            #pragma unroll
            for (int j = 0; j < 8; j++)
                #pragma unroll
                for (int c = 0; c < 4; c++) p4[c] += v[j] * wreg[j * 4 + c];
            #pragma unroll
            for (int off = 1; off <= 8; off <<= 1)
                #pragma unroll
                for (int c = 0; c < 4; c++) p4[c] += __shfl_xor(p4[c], off, 64);
            #pragma unroll
            for (int c = 0; c < 4; c++) p4[c] += bav[c];
            float m = fmaxf(fmaxf(p4[0], p4[1]), fmaxf(p4[2], p4[3]));
            m = fmaxf(m, __shfl_xor(m, 16, 64));
            m = fmaxf(m, __shfl_xor(m, 32, 64));
            float e0 = __expf(p4[0] - m), e1 = __expf(p4[1] - m);
            float e2 = __expf(p4[2] - m), e3 = __expf(p4[3] - m);
            float s = e0 + e1 + e2 + e3;
            s += __shfl_xor(s, 16, 64);
            s += __shfl_xor(s, 32, 64);
            if (fk < 4) {
                float ev = e0;
                ev = (fk == 1) ? e1 : ev;
                ev = (fk == 2) ? e2 : ev;
                ev = (fk == 3) ? e3 : ev;
                aout[(size_t)g * KC + 4 * q + fk] = ev / s;
            }
        }
    }
}

// ---------------- launch ----------------

extern "C" void kernel_launch(void* const* d_in, const int* in_sizes, int n_in,
                              void* d_out, int out_size, void* d_ws, size_t ws_size,
                              hipStream_t stream) {
    const float* x     = (const float*)d_in[0];
    const int*   eidx  = (const int*)d_in[1];
    const float* ew    = (const float*)d_in[2];
    const float* W1    = (const float*)d_in[3];
    const float* b1    = (const float*)d_in[4];
    const float* skip1 = (const float*)d_in[5];
    const float* W2    = (const float*)d_in[6];
    const float* b2    = (const float*)d_in[7];
    const float* skip2 = (const float*)d_in[8];
    const float* Wa    = (const float*)d_in[9];
    const float* ba    = (const float*)d_in[10];
    float* out = (float*)d_out;

    const int* dst = eidx;
    const int* src = eidx + NE;

    char* ws = (char*)d_ws;
    size_t off = 0;
    __hip_bfloat16* T = (__hip_bfloat16*)(ws + off);  off += (size_t)NN * DD * 2;        // 12.8 MB
    __hip_bfloat16* Hb = (__hip_bfloat16*)(ws + off); off += (size_t)NN * DD * 2;        // 12.8 MB
    int2* staging2 = (int2*)(ws + off);               off += (size_t)NCHUNK * CHUNK * 8; // 12.83 MB (own region — r8 aliasing overran Hb)
    unsigned* staging4 = (unsigned*)(ws + off);       off += ((size_t)NB * MAXB + 32) * 4;  // 9.6 MB
    unsigned short* offs = (unsigned short*)(ws + off); off += (size_t)NCHUNK * NBP * 2; // 816 KB
    int* rowptr = (int*)(ws + off);                   off += (size_t)NB * 33 * 4;        // 206 KB
    s8v* Wf1 = (s8v*)(ws + off);                      off += 2048 * 16;                  // 32 KB
    s8v* Wf2 = (s8v*)(ws + off);                      off += 2048 * 16;                  // 32 KB

    k_binsort<<<NCHUNK, BT, 0, stream>>>(dst, src, ew, staging2, offs);
    k_rowsort<<<NB, 256, 0, stream>>>(staging2, offs, staging4, rowptr);

    k_wprep<<<8, 256, 0, stream>>>(W1, Wf1);
    k_wprep<<<8, 256, 0, stream>>>(W2, Wf2);

    int gemm_grid = (NN / 128) + 1;    // 391 blocks x 4 waves x 32 rows
    // layer 1
    k_gemm_mfma<float><<<gemm_grid, 256, 0, stream>>>(x, Wf1, b1, T, NN);
    k_spmm<0><<<NB, 256, 0, stream>>>(T, staging4, rowptr, skip1, Hb, nullptr, nullptr, nullptr);
    // layer 2
    k_gemm_mfma<__hip_bfloat16><<<gemm_grid, 256, 0, stream>>>(Hb, Wf2, b2, T, NN);
    k_spmm<1><<<NB, 256, 0, stream>>>(T, staging4, rowptr, skip2, nullptr, Wa, ba, out);
}

// Round 11
// 267.075 us; speedup vs baseline: 1.1785x; 1.0096x over previous
//
#include <hip/hip_runtime.h>
#include <hip/hip_bf16.h>
#include <hip/hip_fp16.h>

#define NN 50000
#define NE 1600000
#define DD 128
#define KC 16

// Buckets of 16 dst-rows: bucket = dst >> 4.  NN % 16 == 0 -> all buckets full.
#define NB 3125
#define NBP (NB + 1)
#define CHUNK 6144        // edges per binsort block
#define NCHUNK 261        // ceil(NE/CHUNK)
#define BT 1024           // binsort block threads
#define EPT 6             // CHUNK / BT edges per thread
#define MAXB 768          // bucket capacity (avg 512, sigma ~23 -> +11 sigma)
#define SB 784            // staging4 stride per bucket (MAXB + 16 pad slots)

typedef __attribute__((ext_vector_type(8))) short s8v;   // 8 bf16 = 4 VGPRs
typedef __attribute__((ext_vector_type(4))) float f4v;   // 4 fp32 acc
typedef __attribute__((ext_vector_type(2))) float f2v;   // fp32 pair -> v_pk_fma_f32

__device__ __forceinline__ f2v up2(unsigned u) {
    f2v r;
    r.x = __uint_as_float(u << 16);
    r.y = __uint_as_float(u & 0xFFFF0000u);
    return r;
}
__device__ __forceinline__ float wof(unsigned rec) {
    return __half2float(__ushort_as_half((unsigned short)(rec >> 16)));
}

// ---------------- chunk-local counting sort by bucket (single-writer windows) ----------------
// staging2 record (8 B): .x = (row_in_bucket << 16) | src, .y = bits(f32 w)

__global__ __launch_bounds__(BT) void k_binsort(const int* __restrict__ dst,
                                                const int* __restrict__ src,
                                                const float* __restrict__ w,
                                                int2* __restrict__ staging2,
                                                unsigned short* __restrict__ offs) {
    __shared__ int cnt[NB];
    __shared__ int s[BT];
    int t = threadIdx.x;
    int c = blockIdx.x;
    size_t cbase = (size_t)c * CHUNK;
    for (int i = t; i < NB; i += BT) cnt[i] = 0;
    __syncthreads();

    int dreg[EPT], sreg[EPT]; float wreg[EPT];
    #pragma unroll
    for (int j = 0; j < EPT; j++) {
        size_t e = cbase + j * BT + t;
        bool ok = e < NE;
        size_t ee = ok ? e : (NE - 1);
        dreg[j] = dst[ee]; sreg[j] = src[ee]; wreg[j] = w[ee];
        if (!ok) dreg[j] = -1;
        if (ok) atomicAdd(&cnt[dreg[j] >> 4], 1);
    }
    __syncthreads();

    // exclusive scan of cnt[0..NB)
    int v[4]; int sum = 0;
    #pragma unroll
    for (int j = 0; j < 4; j++) { int i = t * 4 + j; v[j] = (i < NB) ? cnt[i] : 0; sum += v[j]; }
    s[t] = sum; __syncthreads();
    for (int off = 1; off < BT; off <<= 1) {
        int u = (t >= off) ? s[t - off] : 0;
        __syncthreads();
        s[t] += u;
        __syncthreads();
    }
    int run = (t == 0) ? 0 : s[t - 1];
    #pragma unroll
    for (int j = 0; j < 4; j++) {
        int i = t * 4 + j;
        if (i < NB) { offs[(size_t)c * NBP + i] = (unsigned short)run; cnt[i] = run; run += v[j]; }
    }
    if (t == BT - 1) offs[(size_t)c * NBP + NB] = (unsigned short)s[BT - 1];
    __syncthreads();

    #pragma unroll
    for (int j = 0; j < EPT; j++) {
        if (dreg[j] >= 0) {
            int b = dreg[j] >> 4;
            int li = atomicAdd(&cnt[b], 1);
            staging2[cbase + li] = make_int2(((dreg[j] & 15) << 16) | sreg[j],
                                            __float_as_int(wreg[j]));
        }
    }
}

// ---------------- per-bucket merge + row sort -> packed 4-B row-sorted staging ----------------
// staging4 record: src | (f16bits(w) << 16).  rowptr[b*17 + r]: LOCAL row offsets.

__global__ __launch_bounds__(256) void k_rowsort(const int2* __restrict__ staging2,
                                                 const unsigned short* __restrict__ offs,
                                                 unsigned* __restrict__ staging4,
                                                 int* __restrict__ rowptr) {
    __shared__ int2 ebuf[MAXB];
    __shared__ unsigned srec[MAXB];
    __shared__ int segoff[NCHUNK + 1];
    __shared__ int cstart[NCHUNK];
    __shared__ int s2[256];
    __shared__ int rcnt[16];
    __shared__ int rowoff[17];
    int b = blockIdx.x, t = threadIdx.x;

    for (int c = t; c < NCHUNK; c += 256) {
        int o0 = offs[(size_t)c * NBP + b];
        int o1 = offs[(size_t)c * NBP + b + 1];
        cstart[c] = o0;
        segoff[c] = o1 - o0;   // temporarily length
    }
    __syncthreads();
    int a0 = (2 * t < NCHUNK) ? segoff[2 * t] : 0;
    int a1 = (2 * t + 1 < NCHUNK) ? segoff[2 * t + 1] : 0;
    s2[t] = a0 + a1; __syncthreads();
    for (int off = 1; off < 256; off <<= 1) {
        int u = (t >= off) ? s2[t - off] : 0;
        __syncthreads();
        s2[t] += u;
        __syncthreads();
    }
    int base0 = (t == 0) ? 0 : s2[t - 1];
    int total = s2[255];
    __syncthreads();
    if (2 * t < NCHUNK) segoff[2 * t] = base0;
    if (2 * t + 1 < NCHUNK) segoff[2 * t + 1] = base0 + a0;
    if (t == 0) segoff[NCHUNK] = total;
    __syncthreads();

    int cnt = total; if (cnt > MAXB) cnt = MAXB;

    // parallel gather: record i -> binary search its chunk
    for (int i = t; i < cnt; i += 256) {
        int lo = 0, hi = NCHUNK;
        while (hi - lo > 1) {
            int mid = (lo + hi) >> 1;
            if (segoff[mid] <= i) lo = mid; else hi = mid;
        }
        ebuf[i] = staging2[(size_t)lo * CHUNK + cstart[lo] + (i - segoff[lo])];
    }
    __syncthreads();

    if (t < 16) rcnt[t] = 0;
    __syncthreads();
    for (int i = t; i < cnt; i += 256) atomicAdd(&rcnt[(unsigned)ebuf[i].x >> 16], 1);
    __syncthreads();
    if (t < 16) {
        int v = rcnt[t];
        int p = v;
        #pragma unroll
        for (int off = 1; off < 16; off <<= 1) {
            int u = __shfl_up(p, off, 64);
            if (t >= off) p += u;
        }
        rowoff[t] = p - v;
        if (t == 15) rowoff[16] = p;
        rcnt[t] = p - v;   // cursor
    }
    __syncthreads();
    for (int i = t; i < cnt; i += 256) {
        int2 rec = ebuf[i];
        int p = atomicAdd(&rcnt[(unsigned)rec.x >> 16], 1);
        unsigned hb = __half_as_ushort(__float2half_rn(__int_as_float(rec.y)));
        srec[p] = ((unsigned)rec.x & 0xFFFFu) | (hb << 16);
    }
    __syncthreads();

    unsigned* outp = staging4 + (size_t)b * SB;
    for (int i = t; i < cnt; i += 256) outp[i] = srec[i];
    if (t < 8) outp[cnt + t] = 0u;   // zero pads (src=0, w=0); SB stride guarantees room
    if (t < 17) rowptr[b * 17 + t] = rowoff[t];
}

// ---------------- W preconvert: fp32 [128][128] -> bf16 frags ----------------

__global__ __launch_bounds__(256) void k_wprep(const float* __restrict__ W,
                                               s8v* __restrict__ Wf) {
    int g = blockIdx.x * 256 + threadIdx.x;   // 2048 threads
    int l = g & 63;
    int kcnt = g >> 6;                         // 0..31
    int kc = kcnt >> 3, nt = kcnt & 7;
    int n = nt * 16 + (l & 15);
    int kb = kc * 32 + (l >> 4) * 8;
    union { s8v v; __hip_bfloat162 h2[4]; } u;
    #pragma unroll
    for (int q = 0; q < 4; q++) {
        float lo = W[(size_t)(kb + 2 * q) * 128 + n];
        float hi = W[(size_t)(kb + 2 * q + 1) * 128 + n];
        u.h2[q] = __float22bfloat162_rn(make_float2(lo, hi));
    }
    Wf[(size_t)kcnt * 64 + l] = u.v;
}

// ---------------- MFMA GEMM: T = bf16( X @ W + bias ), input fp32 or bf16 ----------------

__device__ __forceinline__ s8v load_afrag(const float* p) {
    union { s8v v; __hip_bfloat162 h2[4]; } a;
    float4 f0 = *(const float4*)p;
    float4 f1 = *(const float4*)(p + 4);
    a.h2[0] = __float22bfloat162_rn(make_float2(f0.x, f0.y));
    a.h2[1] = __float22bfloat162_rn(make_float2(f0.z, f0.w));
    a.h2[2] = __float22bfloat162_rn(make_float2(f1.x, f1.y));
    a.h2[3] = __float22bfloat162_rn(make_float2(f1.z, f1.w));
    return a.v;
}
__device__ __forceinline__ s8v load_afrag(const __hip_bfloat16* p) {
    return *(const s8v*)p;
}

template <typename TI>
__global__ __launch_bounds__(256) void k_gemm_mfma(const TI* __restrict__ X,
                                                   const s8v* __restrict__ Wf,
                                                   const float* __restrict__ bias,
                                                   __hip_bfloat16* __restrict__ Out,
                                                   int nrows) {
    int wave = blockIdx.x * 4 + (threadIdx.x >> 6);
    int lane = threadIdx.x & 63;
    int m0 = wave * 32;
    if (m0 >= nrows) return;
    int col = lane & 15;
    int quad = lane >> 4;

    f4v acc[2][8];
    #pragma unroll
    for (int mt = 0; mt < 2; mt++)
        #pragma unroll
        for (int nt = 0; nt < 8; nt++) acc[mt][nt] = (f4v){0.f, 0.f, 0.f, 0.f};

    int row0 = m0 + col;
    int row1 = m0 + 16 + col;
    if (row0 >= nrows) row0 = nrows - 1;
    if (row1 >= nrows) row1 = nrows - 1;
    const TI* xr0 = X + (size_t)row0 * 128 + quad * 8;
    const TI* xr1 = X + (size_t)row1 * 128 + quad * 8;

    #pragma unroll 1
    for (int kc = 0; kc < 4; kc++) {
        s8v a0 = load_afrag(xr0 + kc * 32);
        s8v a1 = load_afrag(xr1 + kc * 32);
        #pragma unroll
        for (int nt = 0; nt < 8; nt++) {
            s8v b = Wf[(size_t)(kc * 8 + nt) * 64 + lane];
            acc[0][nt] = __builtin_amdgcn_mfma_f32_16x16x32_bf16(a0, b, acc[0][nt], 0, 0, 0);
            acc[1][nt] = __builtin_amdgcn_mfma_f32_16x16x32_bf16(a1, b, acc[1][nt], 0, 0, 0);
        }
    }

    float bb[8];
    #pragma unroll
    for (int nt = 0; nt < 8; nt++) bb[nt] = bias[nt * 16 + col];

    #pragma unroll
    for (int mt = 0; mt < 2; mt++) {
        #pragma unroll
        for (int r = 0; r < 4; r++) {
            int row = m0 + mt * 16 + quad * 4 + r;
            if (row < nrows) {
                __hip_bfloat16* orow = Out + (size_t)row * 128 + col;
                #pragma unroll
                for (int nt = 0; nt < 8; nt++) {
                    orow[nt * 16] = __float2bfloat16(acc[mt][nt][r] + bb[nt]);
                }
            }
        }
    }
}

// ---------------- SPMM: one 16-row bucket per block, pre-sorted 4-B records in LDS ----------------
// lane = 16*q + fk : quarter q handles edge (o+q), feature group fk (8 features).
// ASSIGN=0: Hout(bf16) = selu(skip*t + agg).  ASSIGN=1: out = softmax(h@Wa+ba).

template <int ASSIGN>
__global__ __launch_bounds__(256) void k_spmm(const __hip_bfloat16* __restrict__ T,
                                              const unsigned* __restrict__ staging4,
                                              const int* __restrict__ rowptr,
                                              const float* __restrict__ skip,
                                              __hip_bfloat16* __restrict__ Hout,
                                              const float* __restrict__ Wa,
                                              const float* __restrict__ ba,
                                              float* __restrict__ aout) {
    __shared__ __align__(16) unsigned srec[MAXB + 16];
    __shared__ int rowoff[17];
    int b = blockIdx.x;
    int tid = threadIdx.x;

    if (tid < 17) rowoff[tid] = rowptr[b * 17 + tid];
    __syncthreads();
    int cnt = rowoff[16];
    int nv4 = (cnt + 11) >> 2;   // records + 8 pads, in uint4s
    const uint4* sp4 = (const uint4*)(staging4 + (size_t)b * SB);
    for (int i = tid; i < nv4; i += 256) ((uint4*)srec)[i] = sp4[i];
    __syncthreads();

    int wv = tid >> 6, lane = tid & 63;
    int q = lane >> 4;
    int fk = lane & 15;
    const int4* Tv4 = (const int4*)T;   // row = 16 int4 (256 B)

    float sk[8];
    *(float4*)&sk[0] = *(const float4*)(skip + fk * 8);
    *(float4*)&sk[4] = *(const float4*)(skip + fk * 8 + 4);

    float wreg[32];  // ASSIGN: Wa[8fk+j][4q+c]
    float bav[4];
    if (ASSIGN) {
        #pragma unroll
        for (int j = 0; j < 8; j++)
            *(float4*)&wreg[j * 4] = *(const float4*)(Wa + (size_t)(8 * fk + j) * KC + 4 * q);
        #pragma unroll
        for (int c = 0; c < 4; c++) bav[c] = ba[4 * q + c];
    }

    const float scale = 1.0507009873554805f, alpha = 1.6732632423543772f;

    for (int r = wv; r < 16; r += 4) {
        int g = b * 16 + r;
        int o = rowoff[r], oe = rowoff[r + 1];
        f2v a01 = (f2v){0.f, 0.f}, a23 = (f2v){0.f, 0.f};
        f2v a45 = (f2v){0.f, 0.f}, a67 = (f2v){0.f, 0.f};

        for (; o + 8 <= oe; o += 8) {
            unsigned c0 = srec[o + q];
            unsigned c1 = srec[o + 4 + q];
            int4 t0 = Tv4[(size_t)(c0 & 0xFFFFu) * 16 + fk];
            int4 t1 = Tv4[(size_t)(c1 & 0xFFFFu) * 16 + fk];
            float w0 = wof(c0), w1 = wof(c1);
            a01 += w0 * up2(t0.x); a23 += w0 * up2(t0.y);
            a45 += w0 * up2(t0.z); a67 += w0 * up2(t0.w);
            a01 += w1 * up2(t1.x); a23 += w1 * up2(t1.y);
            a45 += w1 * up2(t1.z); a67 += w1 * up2(t1.w);
        }
        for (; o < oe; o += 4) {           // masked tail (pads keep reads safe)
            int i0 = o + q;
            unsigned c0 = srec[i0];
            int4 t0 = Tv4[(size_t)(c0 & 0xFFFFu) * 16 + fk];
            float w0 = (i0 < oe) ? wof(c0) : 0.f;
            a01 += w0 * up2(t0.x); a23 += w0 * up2(t0.y);
            a45 += w0 * up2(t0.z); a67 += w0 * up2(t0.w);
        }

        float acc[8];
        acc[0] = a01.x; acc[1] = a01.y; acc[2] = a23.x; acc[3] = a23.y;
        acc[4] = a45.x; acc[5] = a45.y; acc[6] = a67.x; acc[7] = a67.y;
        #pragma unroll
        for (int j = 0; j < 8; j++) {
            acc[j] += __shfl_xor(acc[j], 16, 64);
            acc[j] += __shfl_xor(acc[j], 32, 64);
        }

        int4 ts = Tv4[(size_t)g * 16 + fk];
        f2v s01 = up2(ts.x), s23 = up2(ts.y), s45 = up2(ts.z), s67 = up2(ts.w);
        float v[8];
        v[0] = sk[0] * s01.x + acc[0]; v[1] = sk[1] * s01.y + acc[1];
        v[2] = sk[2] * s23.x + acc[2]; v[3] = sk[3] * s23.y + acc[3];
        v[4] = sk[4] * s45.x + acc[4]; v[5] = sk[5] * s45.y + acc[5];
        v[6] = sk[6] * s67.x + acc[6]; v[7] = sk[7] * s67.y + acc[7];
        #pragma unroll
        for (int j = 0; j < 8; j++)
            v[j] = scale * (v[j] > 0.f ? v[j] : alpha * (__expf(v[j]) - 1.f));

        if (!ASSIGN) {
            if (q == 0) {
                union { int4 i4; __hip_bfloat162 h2[4]; } pk;
                #pragma unroll
                for (int j = 0; j < 4; j++)
                    pk.h2[j] = __float22bfloat162_rn(make_float2(v[2 * j], v[2 * j + 1]));
                *(int4*)(Hout + (size_t)g * 128 + fk * 8) = pk.i4;
            }
        } else {
            float p4[4] = {0.f, 0.f, 0.f, 0.f};
            #pragma unroll
            for (int j = 0; j < 8; j++)
                #pragma unroll
                for (int c = 0; c < 4; c++) p4[c] += v[j] * wreg[j * 4 + c];
            #pragma unroll
            for (int off = 1; off <= 8; off <<= 1)
                #pragma unroll
                for (int c = 0; c < 4; c++) p4[c] += __shfl_xor(p4[c], off, 64);
            #pragma unroll
            for (int c = 0; c < 4; c++) p4[c] += bav[c];
            float m = fmaxf(fmaxf(p4[0], p4[1]), fmaxf(p4[2], p4[3]));
            m = fmaxf(m, __shfl_xor(m, 16, 64));
            m = fmaxf(m, __shfl_xor(m, 32, 64));
            float e0 = __expf(p4[0] - m), e1 = __expf(p4[1] - m);
            float e2 = __expf(p4[2] - m), e3 = __expf(p4[3] - m);
            float s = e0 + e1 + e2 + e3;
            s += __shfl_xor(s, 16, 64);
            s += __shfl_xor(s, 32, 64);
            if (fk < 4) {
                float ev = e0;
                ev = (fk == 1) ? e1 : ev;
                ev = (fk == 2) ? e2 : ev;
                ev = (fk == 3) ? e3 : ev;
                aout[(size_t)g * KC + 4 * q + fk] = ev / s;
            }
        }
    }
}

// ---------------- launch ----------------

extern "C" void kernel_launch(void* const* d_in, const int* in_sizes, int n_in,
                              void* d_out, int out_size, void* d_ws, size_t ws_size,
                              hipStream_t stream) {
    const float* x     = (const float*)d_in[0];
    const int*   eidx  = (const int*)d_in[1];
    const float* ew    = (const float*)d_in[2];
    const float* W1    = (const float*)d_in[3];
    const float* b1    = (const float*)d_in[4];
    const float* skip1 = (const float*)d_in[5];
    const float* W2    = (const float*)d_in[6];
    const float* b2    = (const float*)d_in[7];
    const float* skip2 = (const float*)d_in[8];
    const float* Wa    = (const float*)d_in[9];
    const float* ba    = (const float*)d_in[10];
    float* out = (float*)d_out;

    const int* dst = eidx;
    const int* src = eidx + NE;

    char* ws = (char*)d_ws;
    size_t off = 0;
    __hip_bfloat16* T = (__hip_bfloat16*)(ws + off);  off += (size_t)NN * DD * 2;        // 12.8 MB
    __hip_bfloat16* Hb = (__hip_bfloat16*)(ws + off); off += (size_t)NN * DD * 2;        // 12.8 MB
    int2* staging2 = (int2*)(ws + off);               off += (size_t)NCHUNK * CHUNK * 8; // 12.83 MB
    unsigned* staging4 = (unsigned*)(ws + off);       off += (size_t)NB * SB * 4;        // 9.8 MB
    unsigned short* offs = (unsigned short*)(ws + off); off += (size_t)NCHUNK * NBP * 2; // 1.63 MB
    int* rowptr = (int*)(ws + off);                   off += (size_t)NB * 17 * 4;        // 212 KB
    s8v* Wf1 = (s8v*)(ws + off);                      off += 2048 * 16;                  // 32 KB
    s8v* Wf2 = (s8v*)(ws + off);                      off += 2048 * 16;                  // 32 KB

    k_binsort<<<NCHUNK, BT, 0, stream>>>(dst, src, ew, staging2, offs);
    k_rowsort<<<NB, 256, 0, stream>>>(staging2, offs, staging4, rowptr);

    k_wprep<<<8, 256, 0, stream>>>(W1, Wf1);
    k_wprep<<<8, 256, 0, stream>>>(W2, Wf2);

    int gemm_grid = (NN / 128) + 1;    // 391 blocks x 4 waves x 32 rows
    // layer 1
    k_gemm_mfma<float><<<gemm_grid, 256, 0, stream>>>(x, Wf1, b1, T, NN);
    k_spmm<0><<<NB, 256, 0, stream>>>(T, staging4, rowptr, skip1, Hb, nullptr, nullptr, nullptr);
    // layer 2
    k_gemm_mfma<__hip_bfloat16><<<gemm_grid, 256, 0, stream>>>(Hb, Wf2, b2, T, NN);
    k_spmm<1><<<NB, 256, 0, stream>>>(T, staging4, rowptr, skip2, nullptr, Wa, ba, out);
}

// Round 12
// 261.942 us; speedup vs baseline: 1.2016x; 1.0196x over previous
//
#include <hip/hip_runtime.h>
#include <hip/hip_bf16.h>
#include <hip/hip_fp16.h>

#define NN 50000
#define NE 1600000
#define DD 128
#define KC 16

// Buckets of 16 dst-rows: bucket = dst >> 4.  NN % 16 == 0 -> all buckets full.
#define NB 3125
#define NBP (NB + 1)
#define CHUNK 6144        // edges per binsort block
#define NCHUNK 261        // ceil(NE/CHUNK)
#define BT 1024           // binsort block threads
#define EPT 6             // CHUNK / BT edges per thread
#define MAXB 768          // bucket capacity (avg 512, sigma ~23 -> +11 sigma)
#define SB 784            // staging4 stride per bucket (MAXB + 16 pad slots)

#define GEMM_BLKS 391     // ceil(50000 / 128), 4 waves x 32 rows per block

typedef __attribute__((ext_vector_type(8))) short s8v;   // 8 bf16 = 4 VGPRs
typedef __attribute__((ext_vector_type(4))) float f4v;   // 4 fp32 acc
typedef __attribute__((ext_vector_type(2))) float f2v;   // fp32 pair -> v_pk_fma_f32

__device__ __forceinline__ f2v up2(unsigned u) {
    f2v r;
    r.x = __uint_as_float(u << 16);
    r.y = __uint_as_float(u & 0xFFFF0000u);
    return r;
}
__device__ __forceinline__ float wof(unsigned rec) {
    return __half2float(__ushort_as_half((unsigned short)(rec >> 16)));
}

// ---------------- W preconvert device body: fp32 [128][128] -> bf16 frag kcnt/lane ----------------

__device__ __forceinline__ void wprep_one(const float* __restrict__ W, s8v* __restrict__ Wf, int g) {
    int l = g & 63;
    int kcnt = g >> 6;                         // 0..31
    int kc = kcnt >> 3, nt = kcnt & 7;
    int n = nt * 16 + (l & 15);
    int kb = kc * 32 + (l >> 4) * 8;
    union { s8v v; __hip_bfloat162 h2[4]; } u;
    #pragma unroll
    for (int q = 0; q < 4; q++) {
        float lo = W[(size_t)(kb + 2 * q) * 128 + n];
        float hi = W[(size_t)(kb + 2 * q + 1) * 128 + n];
        u.h2[q] = __float22bfloat162_rn(make_float2(lo, hi));
    }
    Wf[(size_t)kcnt * 64 + l] = u.v;
}

// ---------------- K1: binsort (blocks 0..260)  ||  wprep W1/W2 (blocks 261..264) ----------------
// staging2 record (8 B): .x = (row_in_bucket << 16) | src, .y = bits(f32 w)

__global__ __launch_bounds__(BT) void k_binprep(const int* __restrict__ dst,
                                                const int* __restrict__ src,
                                                const float* __restrict__ w,
                                                int2* __restrict__ staging2,
                                                unsigned short* __restrict__ offs,
                                                const float* __restrict__ W1,
                                                const float* __restrict__ W2,
                                                s8v* __restrict__ Wf1,
                                                s8v* __restrict__ Wf2) {
    __shared__ int cnt[NB];
    __shared__ int s[BT];
    int t = threadIdx.x;
    int bid = blockIdx.x;

    if (bid >= NCHUNK) {                       // wprep branch: 4 blocks x 1024 = 2 x 2048 pairs
        int idx = bid - NCHUNK;                // 0..3
        int g = (idx & 1) * 1024 + t;          // 0..2047
        if (idx < 2) wprep_one(W1, Wf1, g);
        else         wprep_one(W2, Wf2, g);
        return;
    }

    int c = bid;
    size_t cbase = (size_t)c * CHUNK;
    for (int i = t; i < NB; i += BT) cnt[i] = 0;
    __syncthreads();

    int dreg[EPT], sreg[EPT]; float wreg[EPT];
    #pragma unroll
    for (int j = 0; j < EPT; j++) {
        size_t e = cbase + j * BT + t;
        bool ok = e < NE;
        size_t ee = ok ? e : (NE - 1);
        dreg[j] = dst[ee]; sreg[j] = src[ee]; wreg[j] = w[ee];
        if (!ok) dreg[j] = -1;
        if (ok) atomicAdd(&cnt[dreg[j] >> 4], 1);
    }
    __syncthreads();

    // exclusive scan of cnt[0..NB)
    int v[4]; int sum = 0;
    #pragma unroll
    for (int j = 0; j < 4; j++) { int i = t * 4 + j; v[j] = (i < NB) ? cnt[i] : 0; sum += v[j]; }
    s[t] = sum; __syncthreads();
    for (int off = 1; off < BT; off <<= 1) {
        int u = (t >= off) ? s[t - off] : 0;
        __syncthreads();
        s[t] += u;
        __syncthreads();
    }
    int run = (t == 0) ? 0 : s[t - 1];
    #pragma unroll
    for (int j = 0; j < 4; j++) {
        int i = t * 4 + j;
        if (i < NB) { offs[(size_t)c * NBP + i] = (unsigned short)run; cnt[i] = run; run += v[j]; }
    }
    if (t == BT - 1) offs[(size_t)c * NBP + NB] = (unsigned short)s[BT - 1];
    __syncthreads();

    #pragma unroll
    for (int j = 0; j < EPT; j++) {
        if (dreg[j] >= 0) {
            int b = dreg[j] >> 4;
            int li = atomicAdd(&cnt[b], 1);
            staging2[cbase + li] = make_int2(((dreg[j] & 15) << 16) | sreg[j],
                                            __float_as_int(wreg[j]));
        }
    }
}

// ---------------- MFMA GEMM device body: Out = bf16( X @ W + bias ) for one wave ----------------

__device__ __forceinline__ s8v load_afrag(const float* p) {
    union { s8v v; __hip_bfloat162 h2[4]; } a;
    float4 f0 = *(const float4*)p;
    float4 f1 = *(const float4*)(p + 4);
    a.h2[0] = __float22bfloat162_rn(make_float2(f0.x, f0.y));
    a.h2[1] = __float22bfloat162_rn(make_float2(f0.z, f0.w));
    a.h2[2] = __float22bfloat162_rn(make_float2(f1.x, f1.y));
    a.h2[3] = __float22bfloat162_rn(make_float2(f1.z, f1.w));
    return a.v;
}
__device__ __forceinline__ s8v load_afrag(const __hip_bfloat16* p) {
    return *(const s8v*)p;
}

template <typename TI>
__device__ __forceinline__ void gemm_body(const TI* __restrict__ X,
                                          const s8v* __restrict__ Wf,
                                          const float* __restrict__ bias,
                                          __hip_bfloat16* __restrict__ Out,
                                          int nrows, int wave, int lane) {
    int m0 = wave * 32;
    if (m0 >= nrows) return;
    int col = lane & 15;
    int quad = lane >> 4;

    f4v acc[2][8];
    #pragma unroll
    for (int mt = 0; mt < 2; mt++)
        #pragma unroll
        for (int nt = 0; nt < 8; nt++) acc[mt][nt] = (f4v){0.f, 0.f, 0.f, 0.f};

    int row0 = m0 + col;
    int row1 = m0 + 16 + col;
    if (row0 >= nrows) row0 = nrows - 1;
    if (row1 >= nrows) row1 = nrows - 1;
    const TI* xr0 = X + (size_t)row0 * 128 + quad * 8;
    const TI* xr1 = X + (size_t)row1 * 128 + quad * 8;

    #pragma unroll 1
    for (int kc = 0; kc < 4; kc++) {
        s8v a0 = load_afrag(xr0 + kc * 32);
        s8v a1 = load_afrag(xr1 + kc * 32);
        #pragma unroll
        for (int nt = 0; nt < 8; nt++) {
            s8v b = Wf[(size_t)(kc * 8 + nt) * 64 + lane];
            acc[0][nt] = __builtin_amdgcn_mfma_f32_16x16x32_bf16(a0, b, acc[0][nt], 0, 0, 0);
            acc[1][nt] = __builtin_amdgcn_mfma_f32_16x16x32_bf16(a1, b, acc[1][nt], 0, 0, 0);
        }
    }

    float bb[8];
    #pragma unroll
    for (int nt = 0; nt < 8; nt++) bb[nt] = bias[nt * 16 + col];

    #pragma unroll
    for (int mt = 0; mt < 2; mt++) {
        #pragma unroll
        for (int r = 0; r < 4; r++) {
            int row = m0 + mt * 16 + quad * 4 + r;
            if (row < nrows) {
                __hip_bfloat16* orow = Out + (size_t)row * 128 + col;
                #pragma unroll
                for (int nt = 0; nt < 8; nt++) {
                    orow[nt * 16] = __float2bfloat16(acc[mt][nt][r] + bb[nt]);
                }
            }
        }
    }
}

// ---------------- K2: rowsort (blocks 0..NB-1)  ||  gemm layer-1 (blocks NB..NB+390) ----------------
// staging4 record: src | (f16bits(w) << 16).  rowptr[b*17 + r]: LOCAL row offsets.

__global__ __launch_bounds__(256) void k_sortgemm(const int2* __restrict__ staging2,
                                                  const unsigned short* __restrict__ offs,
                                                  unsigned* __restrict__ staging4,
                                                  int* __restrict__ rowptr,
                                                  const float* __restrict__ x,
                                                  const s8v* __restrict__ Wf1,
                                                  const float* __restrict__ b1,
                                                  __hip_bfloat16* __restrict__ T) {
    __shared__ int2 ebuf[MAXB];
    __shared__ unsigned srec[MAXB];
    __shared__ int segoff[NCHUNK + 1];
    __shared__ int cstart[NCHUNK];
    __shared__ int s2[256];
    __shared__ int rcnt[16];
    __shared__ int rowoff[17];
    int bid = blockIdx.x, t = threadIdx.x;

    if (bid >= NB) {   // gemm layer-1 branch
        int wave = (bid - NB) * 4 + (t >> 6);
        gemm_body<float>(x, Wf1, b1, T, NN, wave, t & 63);
        return;
    }

    int b = bid;
    for (int c = t; c < NCHUNK; c += 256) {
        int o0 = offs[(size_t)c * NBP + b];
        int o1 = offs[(size_t)c * NBP + b + 1];
        cstart[c] = o0;
        segoff[c] = o1 - o0;   // temporarily length
    }
    __syncthreads();
    int a0 = (2 * t < NCHUNK) ? segoff[2 * t] : 0;
    int a1 = (2 * t + 1 < NCHUNK) ? segoff[2 * t + 1] : 0;
    s2[t] = a0 + a1; __syncthreads();
    for (int off = 1; off < 256; off <<= 1) {
        int u = (t >= off) ? s2[t - off] : 0;
        __syncthreads();
        s2[t] += u;
        __syncthreads();
    }
    int base0 = (t == 0) ? 0 : s2[t - 1];
    int total = s2[255];
    __syncthreads();
    if (2 * t < NCHUNK) segoff[2 * t] = base0;
    if (2 * t + 1 < NCHUNK) segoff[2 * t + 1] = base0 + a0;
    if (t == 0) segoff[NCHUNK] = total;
    __syncthreads();

    int cnt = total; if (cnt > MAXB) cnt = MAXB;

    // parallel gather: record i -> binary search its chunk
    for (int i = t; i < cnt; i += 256) {
        int lo = 0, hi = NCHUNK;
        while (hi - lo > 1) {
            int mid = (lo + hi) >> 1;
            if (segoff[mid] <= i) lo = mid; else hi = mid;
        }
        ebuf[i] = staging2[(size_t)lo * CHUNK + cstart[lo] + (i - segoff[lo])];
    }
    __syncthreads();

    if (t < 16) rcnt[t] = 0;
    __syncthreads();
    for (int i = t; i < cnt; i += 256) atomicAdd(&rcnt[(unsigned)ebuf[i].x >> 16], 1);
    __syncthreads();
    if (t < 16) {
        int v = rcnt[t];
        int p = v;
        #pragma unroll
        for (int off = 1; off < 16; off <<= 1) {
            int u = __shfl_up(p, off, 64);
            if (t >= off) p += u;
        }
        rowoff[t] = p - v;
        if (t == 15) rowoff[16] = p;
        rcnt[t] = p - v;   // cursor
    }
    __syncthreads();
    for (int i = t; i < cnt; i += 256) {
        int2 rec = ebuf[i];
        int p = atomicAdd(&rcnt[(unsigned)rec.x >> 16], 1);
        unsigned hb = __half_as_ushort(__float2half_rn(__int_as_float(rec.y)));
        srec[p] = ((unsigned)rec.x & 0xFFFFu) | (hb << 16);
    }
    __syncthreads();

    unsigned* outp = staging4 + (size_t)b * SB;
    for (int i = t; i < cnt; i += 256) outp[i] = srec[i];
    if (t < 8) outp[cnt + t] = 0u;   // zero pads (src=0, w=0); SB stride guarantees room
    if (t < 17) rowptr[b * 17 + t] = rowoff[t];
}

// ---------------- GEMM layer-2 (standalone) ----------------

__global__ __launch_bounds__(256) void k_gemm2(const __hip_bfloat16* __restrict__ X,
                                               const s8v* __restrict__ Wf,
                                               const float* __restrict__ bias,
                                               __hip_bfloat16* __restrict__ Out) {
    int wave = blockIdx.x * 4 + (threadIdx.x >> 6);
    gemm_body<__hip_bfloat16>(X, Wf, bias, Out, NN, wave, threadIdx.x & 63);
}

// ---------------- SPMM: one 16-row bucket per block, pre-sorted 4-B records in LDS ----------------
// lane = 16*q + fk : quarter q handles edge (o+q), feature group fk (8 features).
// ASSIGN=0: Hout(bf16) = selu(skip*t + agg).  ASSIGN=1: out = softmax(h@Wa+ba).

template <int ASSIGN>
__global__ __launch_bounds__(256) void k_spmm(const __hip_bfloat16* __restrict__ T,
                                              const unsigned* __restrict__ staging4,
                                              const int* __restrict__ rowptr,
                                              const float* __restrict__ skip,
                                              __hip_bfloat16* __restrict__ Hout,
                                              const float* __restrict__ Wa,
                                              const float* __restrict__ ba,
                                              float* __restrict__ aout) {
    __shared__ __align__(16) unsigned srec[MAXB + 16];
    __shared__ int rowoff[17];
    int b = blockIdx.x;
    int tid = threadIdx.x;

    if (tid < 17) rowoff[tid] = rowptr[b * 17 + tid];
    __syncthreads();
    int cnt = rowoff[16];
    int nv4 = (cnt + 11) >> 2;   // records + 8 pads, in uint4s
    const uint4* sp4 = (const uint4*)(staging4 + (size_t)b * SB);
    for (int i = tid; i < nv4; i += 256) ((uint4*)srec)[i] = sp4[i];
    __syncthreads();

    int wv = tid >> 6, lane = tid & 63;
    int q = lane >> 4;
    int fk = lane & 15;
    const int4* Tv4 = (const int4*)T;   // row = 16 int4 (256 B)

    float sk[8];
    *(float4*)&sk[0] = *(const float4*)(skip + fk * 8);
    *(float4*)&sk[4] = *(const float4*)(skip + fk * 8 + 4);

    float wreg[32];  // ASSIGN: Wa[8fk+j][4q+c]
    float bav[4];
    if (ASSIGN) {
        #pragma unroll
        for (int j = 0; j < 8; j++)
            *(float4*)&wreg[j * 4] = *(const float4*)(Wa + (size_t)(8 * fk + j) * KC + 4 * q);
        #pragma unroll
        for (int c = 0; c < 4; c++) bav[c] = ba[4 * q + c];
    }

    const float scale = 1.0507009873554805f, alpha = 1.6732632423543772f;

    for (int r = wv; r < 16; r += 4) {
        int g = b * 16 + r;
        int o = rowoff[r], oe = rowoff[r + 1];
        f2v a01 = (f2v){0.f, 0.f}, a23 = (f2v){0.f, 0.f};
        f2v a45 = (f2v){0.f, 0.f}, a67 = (f2v){0.f, 0.f};

        for (; o + 16 <= oe; o += 16) {   // 4 independent 16B gathers in flight
            unsigned c0 = srec[o + q];
            unsigned c1 = srec[o + 4 + q];
            unsigned c2 = srec[o + 8 + q];
            unsigned c3 = srec[o + 12 + q];
            int4 t0 = Tv4[(size_t)(c0 & 0xFFFFu) * 16 + fk];
            int4 t1 = Tv4[(size_t)(c1 & 0xFFFFu) * 16 + fk];
            int4 t2 = Tv4[(size_t)(c2 & 0xFFFFu) * 16 + fk];
            int4 t3 = Tv4[(size_t)(c3 & 0xFFFFu) * 16 + fk];
            float w0 = wof(c0), w1 = wof(c1), w2 = wof(c2), w3 = wof(c3);
            a01 += w0 * up2(t0.x); a23 += w0 * up2(t0.y);
            a45 += w0 * up2(t0.z); a67 += w0 * up2(t0.w);
            a01 += w1 * up2(t1.x); a23 += w1 * up2(t1.y);
            a45 += w1 * up2(t1.z); a67 += w1 * up2(t1.w);
            a01 += w2 * up2(t2.x); a23 += w2 * up2(t2.y);
            a45 += w2 * up2(t2.z); a67 += w2 * up2(t2.w);
            a01 += w3 * up2(t3.x); a23 += w3 * up2(t3.y);
            a45 += w3 * up2(t3.z); a67 += w3 * up2(t3.w);
        }
        for (; o + 8 <= oe; o += 8) {
            unsigned c0 = srec[o + q];
            unsigned c1 = srec[o + 4 + q];
            int4 t0 = Tv4[(size_t)(c0 & 0xFFFFu) * 16 + fk];
            int4 t1 = Tv4[(size_t)(c1 & 0xFFFFu) * 16 + fk];
            float w0 = wof(c0), w1 = wof(c1);
            a01 += w0 * up2(t0.x); a23 += w0 * up2(t0.y);
            a45 += w0 * up2(t0.z); a67 += w0 * up2(t0.w);
            a01 += w1 * up2(t1.x); a23 += w1 * up2(t1.y);
            a45 += w1 * up2(t1.z); a67 += w1 * up2(t1.w);
        }
        for (; o < oe; o += 4) {           // masked tail (pads keep reads safe)
            int i0 = o + q;
            unsigned c0 = srec[i0];
            int4 t0 = Tv4[(size_t)(c0 & 0xFFFFu) * 16 + fk];
            float w0 = (i0 < oe) ? wof(c0) : 0.f;
            a01 += w0 * up2(t0.x); a23 += w0 * up2(t0.y);
            a45 += w0 * up2(t0.z); a67 += w0 * up2(t0.w);
        }

        float acc[8];
        acc[0] = a01.x; acc[1] = a01.y; acc[2] = a23.x; acc[3] = a23.y;
        acc[4] = a45.x; acc[5] = a45.y; acc[6] = a67.x; acc[7] = a67.y;
        #pragma unroll
        for (int j = 0; j < 8; j++) {
            acc[j] += __shfl_xor(acc[j], 16, 64);
            acc[j] += __shfl_xor(acc[j], 32, 64);
        }

        int4 ts = Tv4[(size_t)g * 16 + fk];
        f2v s01 = up2(ts.x), s23 = up2(ts.y), s45 = up2(ts.z), s67 = up2(ts.w);
        float v[8];
        v[0] = sk[0] * s01.x + acc[0]; v[1] = sk[1] * s01.y + acc[1];
        v[2] = sk[2] * s23.x + acc[2]; v[3] = sk[3] * s23.y + acc[3];
        v[4] = sk[4] * s45.x + acc[4]; v[5] = sk[5] * s45.y + acc[5];
        v[6] = sk[6] * s67.x + acc[6]; v[7] = sk[7] * s67.y + acc[7];
        #pragma unroll
        for (int j = 0; j < 8; j++)
            v[j] = scale * (v[j] > 0.f ? v[j] : alpha * (__expf(v[j]) - 1.f));

        if (!ASSIGN) {
            if (q == 0) {
                union { int4 i4; __hip_bfloat162 h2[4]; } pk;
                #pragma unroll
                for (int j = 0; j < 4; j++)
                    pk.h2[j] = __float22bfloat162_rn(make_float2(v[2 * j], v[2 * j + 1]));
                *(int4*)(Hout + (size_t)g * 128 + fk * 8) = pk.i4;
            }
        } else {
            float p4[4] = {0.f, 0.f, 0.f, 0.f};
            #pragma unroll
            for (int j = 0; j < 8; j++)
                #pragma unroll
                for (int c = 0; c < 4; c++) p4[c] += v[j] * wreg[j * 4 + c];
            #pragma unroll
            for (int off = 1; off <= 8; off <<= 1)
                #pragma unroll
                for (int c = 0; c < 4; c++) p4[c] += __shfl_xor(p4[c], off, 64);
            #pragma unroll
            for (int c = 0; c < 4; c++) p4[c] += bav[c];
            float m = fmaxf(fmaxf(p4[0], p4[1]), fmaxf(p4[2], p4[3]));
            m = fmaxf(m, __shfl_xor(m, 16, 64));
            m = fmaxf(m, __shfl_xor(m, 32, 64));
            float e0 = __expf(p4[0] - m), e1 = __expf(p4[1] - m);
            float e2 = __expf(p4[2] - m), e3 = __expf(p4[3] - m);
            float s = e0 + e1 + e2 + e3;
            s += __shfl_xor(s, 16, 64);
            s += __shfl_xor(s, 32, 64);
            if (fk < 4) {
                float ev = e0;
                ev = (fk == 1) ? e1 : ev;
                ev = (fk == 2) ? e2 : ev;
                ev = (fk == 3) ? e3 : ev;
                aout[(size_t)g * KC + 4 * q + fk] = ev / s;
            }
        }
    }
}

// ---------------- launch ----------------

extern "C" void kernel_launch(void* const* d_in, const int* in_sizes, int n_in,
                              void* d_out, int out_size, void* d_ws, size_t ws_size,
                              hipStream_t stream) {
    const float* x     = (const float*)d_in[0];
    const int*   eidx  = (const int*)d_in[1];
    const float* ew    = (const float*)d_in[2];
    const float* W1    = (const float*)d_in[3];
    const float* b1    = (const float*)d_in[4];
    const float* skip1 = (const float*)d_in[5];
    const float* W2    = (const float*)d_in[6];
    const float* b2    = (const float*)d_in[7];
    const float* skip2 = (const float*)d_in[8];
    const float* Wa    = (const float*)d_in[9];
    const float* ba    = (const float*)d_in[10];
    float* out = (float*)d_out;

    const int* dst = eidx;
    const int* src = eidx + NE;

    char* ws = (char*)d_ws;
    size_t off = 0;
    __hip_bfloat16* T = (__hip_bfloat16*)(ws + off);  off += (size_t)NN * DD * 2;        // 12.8 MB
    __hip_bfloat16* Hb = (__hip_bfloat16*)(ws + off); off += (size_t)NN * DD * 2;        // 12.8 MB
    int2* staging2 = (int2*)(ws + off);               off += (size_t)NCHUNK * CHUNK * 8; // 12.83 MB
    unsigned* staging4 = (unsigned*)(ws + off);       off += (size_t)NB * SB * 4;        // 9.8 MB
    unsigned short* offs = (unsigned short*)(ws + off); off += (size_t)NCHUNK * NBP * 2; // 1.63 MB
    int* rowptr = (int*)(ws + off);                   off += (size_t)NB * 17 * 4;        // 212 KB
    s8v* Wf1 = (s8v*)(ws + off);                      off += 2048 * 16;                  // 32 KB
    s8v* Wf2 = (s8v*)(ws + off);                      off += 2048 * 16;                  // 32 KB

    // K1: binsort || wprep(W1) || wprep(W2)
    k_binprep<<<NCHUNK + 4, BT, 0, stream>>>(dst, src, ew, staging2, offs, W1, W2, Wf1, Wf2);
    // K2: rowsort || gemm layer-1
    k_sortgemm<<<NB + GEMM_BLKS, 256, 0, stream>>>(staging2, offs, staging4, rowptr,
                                                   x, Wf1, b1, T);
    // layer-1 aggregate
    k_spmm<0><<<NB, 256, 0, stream>>>(T, staging4, rowptr, skip1, Hb, nullptr, nullptr, nullptr);
    // layer-2 GEMM
    k_gemm2<<<GEMM_BLKS, 256, 0, stream>>>(Hb, Wf2, b2, T);
    // layer-2 aggregate + assignment
    k_spmm<1><<<NB, 256, 0, stream>>>(T, staging4, rowptr, skip2, nullptr, Wa, ba, out);
}

// Round 13
// 250.013 us; speedup vs baseline: 1.2589x; 1.0477x over previous
//
#include <hip/hip_runtime.h>
#include <hip/hip_bf16.h>
#include <hip/hip_fp16.h>

#define NN 50000
#define NE 1600000
#define DD 128
#define KC 16

// Buckets of 16 dst-rows: bucket = dst >> 4.  NN % 16 == 0 -> all buckets full.
#define NB 3125
#define NBP (NB + 1)
#define CHUNK 6144        // edges per binsort block
#define NCHUNK 261        // ceil(NE/CHUNK)
#define BT 1024           // binsort block threads
#define EPT 6             // CHUNK / BT edges per thread
#define MAXB 768          // bucket capacity (avg 512, sigma ~23 -> +11 sigma)
#define SB 784            // staging4 stride per bucket (MAXB + 16 pad slots)

#define GEMM_BLKS 391     // ceil(50000 / 128), 4 waves x 32 rows per block
#define HB_LD 136         // hbuf row stride in bf16 (128 + 8 pad -> conflict-free ds_read_b128)

typedef __attribute__((ext_vector_type(8))) short s8v;   // 8 bf16 = 4 VGPRs
typedef __attribute__((ext_vector_type(4))) float f4v;   // 4 fp32 acc
typedef __attribute__((ext_vector_type(2))) float f2v;   // fp32 pair -> v_pk_fma_f32

__device__ __forceinline__ f2v up2(unsigned u) {
    f2v r;
    r.x = __uint_as_float(u << 16);
    r.y = __uint_as_float(u & 0xFFFF0000u);
    return r;
}
__device__ __forceinline__ float wof(unsigned rec) {
    return __half2float(__ushort_as_half((unsigned short)(rec >> 16)));
}

// ---------------- W preconvert device body: fp32 [128][128] -> bf16 frag kcnt/lane ----------------

__device__ __forceinline__ void wprep_one(const float* __restrict__ W, s8v* __restrict__ Wf, int g) {
    int l = g & 63;
    int kcnt = g >> 6;                         // 0..31
    int kc = kcnt >> 3, nt = kcnt & 7;
    int n = nt * 16 + (l & 15);
    int kb = kc * 32 + (l >> 4) * 8;
    union { s8v v; __hip_bfloat162 h2[4]; } u;
    #pragma unroll
    for (int q = 0; q < 4; q++) {
        float lo = W[(size_t)(kb + 2 * q) * 128 + n];
        float hi = W[(size_t)(kb + 2 * q + 1) * 128 + n];
        u.h2[q] = __float22bfloat162_rn(make_float2(lo, hi));
    }
    Wf[(size_t)kcnt * 64 + l] = u.v;
}

// ---------------- K1: binsort (blocks 0..260)  ||  wprep W1/W2 (blocks 261..264) ----------------
// staging2 record (8 B): .x = (row_in_bucket << 16) | src, .y = bits(f32 w)

__global__ __launch_bounds__(BT) void k_binprep(const int* __restrict__ dst,
                                                const int* __restrict__ src,
                                                const float* __restrict__ w,
                                                int2* __restrict__ staging2,
                                                unsigned short* __restrict__ offs,
                                                const float* __restrict__ W1,
                                                const float* __restrict__ W2,
                                                s8v* __restrict__ Wf1,
                                                s8v* __restrict__ Wf2) {
    __shared__ int cnt[NB];
    __shared__ int s[BT];
    int t = threadIdx.x;
    int bid = blockIdx.x;

    if (bid >= NCHUNK) {                       // wprep branch: 4 blocks x 1024 = 2 x 2048 pairs
        int idx = bid - NCHUNK;                // 0..3
        int g = (idx & 1) * 1024 + t;          // 0..2047
        if (idx < 2) wprep_one(W1, Wf1, g);
        else         wprep_one(W2, Wf2, g);
        return;
    }

    int c = bid;
    size_t cbase = (size_t)c * CHUNK;
    for (int i = t; i < NB; i += BT) cnt[i] = 0;
    __syncthreads();

    int dreg[EPT], sreg[EPT]; float wreg[EPT];
    #pragma unroll
    for (int j = 0; j < EPT; j++) {
        size_t e = cbase + j * BT + t;
        bool ok = e < NE;
        size_t ee = ok ? e : (NE - 1);
        dreg[j] = dst[ee]; sreg[j] = src[ee]; wreg[j] = w[ee];
        if (!ok) dreg[j] = -1;
        if (ok) atomicAdd(&cnt[dreg[j] >> 4], 1);
    }
    __syncthreads();

    // exclusive scan of cnt[0..NB)
    int v[4]; int sum = 0;
    #pragma unroll
    for (int j = 0; j < 4; j++) { int i = t * 4 + j; v[j] = (i < NB) ? cnt[i] : 0; sum += v[j]; }
    s[t] = sum; __syncthreads();
    for (int off = 1; off < BT; off <<= 1) {
        int u = (t >= off) ? s[t - off] : 0;
        __syncthreads();
        s[t] += u;
        __syncthreads();
    }
    int run = (t == 0) ? 0 : s[t - 1];
    #pragma unroll
    for (int j = 0; j < 4; j++) {
        int i = t * 4 + j;
        if (i < NB) { offs[(size_t)c * NBP + i] = (unsigned short)run; cnt[i] = run; run += v[j]; }
    }
    if (t == BT - 1) offs[(size_t)c * NBP + NB] = (unsigned short)s[BT - 1];
    __syncthreads();

    #pragma unroll
    for (int j = 0; j < EPT; j++) {
        if (dreg[j] >= 0) {
            int b = dreg[j] >> 4;
            int li = atomicAdd(&cnt[b], 1);
            staging2[cbase + li] = make_int2(((dreg[j] & 15) << 16) | sreg[j],
                                            __float_as_int(wreg[j]));
        }
    }
}

// ---------------- MFMA GEMM device body: Out = bf16( X @ W + bias ) for one wave ----------------

__device__ __forceinline__ s8v load_afrag(const float* p) {
    union { s8v v; __hip_bfloat162 h2[4]; } a;
    float4 f0 = *(const float4*)p;
    float4 f1 = *(const float4*)(p + 4);
    a.h2[0] = __float22bfloat162_rn(make_float2(f0.x, f0.y));
    a.h2[1] = __float22bfloat162_rn(make_float2(f0.z, f0.w));
    a.h2[2] = __float22bfloat162_rn(make_float2(f1.x, f1.y));
    a.h2[3] = __float22bfloat162_rn(make_float2(f1.z, f1.w));
    return a.v;
}

template <typename TI>
__device__ __forceinline__ void gemm_body(const TI* __restrict__ X,
                                          const s8v* __restrict__ Wf,
                                          const float* __restrict__ bias,
                                          __hip_bfloat16* __restrict__ Out,
                                          int nrows, int wave, int lane) {
    int m0 = wave * 32;
    if (m0 >= nrows) return;
    int col = lane & 15;
    int quad = lane >> 4;

    f4v acc[2][8];
    #pragma unroll
    for (int mt = 0; mt < 2; mt++)
        #pragma unroll
        for (int nt = 0; nt < 8; nt++) acc[mt][nt] = (f4v){0.f, 0.f, 0.f, 0.f};

    int row0 = m0 + col;
    int row1 = m0 + 16 + col;
    if (row0 >= nrows) row0 = nrows - 1;
    if (row1 >= nrows) row1 = nrows - 1;
    const TI* xr0 = X + (size_t)row0 * 128 + quad * 8;
    const TI* xr1 = X + (size_t)row1 * 128 + quad * 8;

    #pragma unroll 1
    for (int kc = 0; kc < 4; kc++) {
        s8v a0 = load_afrag(xr0 + kc * 32);
        s8v a1 = load_afrag(xr1 + kc * 32);
        #pragma unroll
        for (int nt = 0; nt < 8; nt++) {
            s8v b = Wf[(size_t)(kc * 8 + nt) * 64 + lane];
            acc[0][nt] = __builtin_amdgcn_mfma_f32_16x16x32_bf16(a0, b, acc[0][nt], 0, 0, 0);
            acc[1][nt] = __builtin_amdgcn_mfma_f32_16x16x32_bf16(a1, b, acc[1][nt], 0, 0, 0);
        }
    }

    float bb[8];
    #pragma unroll
    for (int nt = 0; nt < 8; nt++) bb[nt] = bias[nt * 16 + col];

    #pragma unroll
    for (int mt = 0; mt < 2; mt++) {
        #pragma unroll
        for (int r = 0; r < 4; r++) {
            int row = m0 + mt * 16 + quad * 4 + r;
            if (row < nrows) {
                __hip_bfloat16* orow = Out + (size_t)row * 128 + col;
                #pragma unroll
                for (int nt = 0; nt < 8; nt++) {
                    orow[nt * 16] = __float2bfloat16(acc[mt][nt][r] + bb[nt]);
                }
            }
        }
    }
}

// ---------------- K2: rowsort (blocks 0..NB-1)  ||  gemm layer-1 (blocks NB..NB+390) ----------------
// staging4 record: src | (f16bits(w) << 16).  rowptr[b*17 + r]: LOCAL row offsets.

__global__ __launch_bounds__(256) void k_sortgemm(const int2* __restrict__ staging2,
                                                  const unsigned short* __restrict__ offs,
                                                  unsigned* __restrict__ staging4,
                                                  int* __restrict__ rowptr,
                                                  const float* __restrict__ x,
                                                  const s8v* __restrict__ Wf1,
                                                  const float* __restrict__ b1,
                                                  __hip_bfloat16* __restrict__ T) {
    __shared__ int2 ebuf[MAXB];
    __shared__ unsigned srec[MAXB];
    __shared__ int segoff[NCHUNK + 1];
    __shared__ int cstart[NCHUNK];
    __shared__ int s2[256];
    __shared__ int rcnt[16];
    __shared__ int rowoff[17];
    int bid = blockIdx.x, t = threadIdx.x;

    if (bid >= NB) {   // gemm layer-1 branch
        int wave = (bid - NB) * 4 + (t >> 6);
        gemm_body<float>(x, Wf1, b1, T, NN, wave, t & 63);
        return;
    }

    int b = bid;
    for (int c = t; c < NCHUNK; c += 256) {
        int o0 = offs[(size_t)c * NBP + b];
        int o1 = offs[(size_t)c * NBP + b + 1];
        cstart[c] = o0;
        segoff[c] = o1 - o0;   // temporarily length
    }
    __syncthreads();
    int a0 = (2 * t < NCHUNK) ? segoff[2 * t] : 0;
    int a1 = (2 * t + 1 < NCHUNK) ? segoff[2 * t + 1] : 0;
    s2[t] = a0 + a1; __syncthreads();
    for (int off = 1; off < 256; off <<= 1) {
        int u = (t >= off) ? s2[t - off] : 0;
        __syncthreads();
        s2[t] += u;
        __syncthreads();
    }
    int base0 = (t == 0) ? 0 : s2[t - 1];
    int total = s2[255];
    __syncthreads();
    if (2 * t < NCHUNK) segoff[2 * t] = base0;
    if (2 * t + 1 < NCHUNK) segoff[2 * t + 1] = base0 + a0;
    if (t == 0) segoff[NCHUNK] = total;
    __syncthreads();

    int cnt = total; if (cnt > MAXB) cnt = MAXB;

    // parallel gather: record i -> binary search its chunk
    for (int i = t; i < cnt; i += 256) {
        int lo = 0, hi = NCHUNK;
        while (hi - lo > 1) {
            int mid = (lo + hi) >> 1;
            if (segoff[mid] <= i) lo = mid; else hi = mid;
        }
        ebuf[i] = staging2[(size_t)lo * CHUNK + cstart[lo] + (i - segoff[lo])];
    }
    __syncthreads();

    if (t < 16) rcnt[t] = 0;
    __syncthreads();
    for (int i = t; i < cnt; i += 256) atomicAdd(&rcnt[(unsigned)ebuf[i].x >> 16], 1);
    __syncthreads();
    if (t < 16) {
        int v = rcnt[t];
        int p = v;
        #pragma unroll
        for (int off = 1; off < 16; off <<= 1) {
            int u = __shfl_up(p, off, 64);
            if (t >= off) p += u;
        }
        rowoff[t] = p - v;
        if (t == 15) rowoff[16] = p;
        rcnt[t] = p - v;   // cursor
    }
    __syncthreads();
    for (int i = t; i < cnt; i += 256) {
        int2 rec = ebuf[i];
        int p = atomicAdd(&rcnt[(unsigned)rec.x >> 16], 1);
        unsigned hb = __half_as_ushort(__float2half_rn(__int_as_float(rec.y)));
        srec[p] = ((unsigned)rec.x & 0xFFFFu) | (hb << 16);
    }
    __syncthreads();

    unsigned* outp = staging4 + (size_t)b * SB;
    for (int i = t; i < cnt; i += 256) outp[i] = srec[i];
    if (t < 8) outp[cnt + t] = 0u;   // zero pads (src=0, w=0); SB stride guarantees room
    if (t < 17) rowptr[b * 17 + t] = rowoff[t];
}

// ---------------- SPMM: one 16-row bucket per block, pre-sorted 4-B records in LDS ----------------
// lane = 16*q + fk : quarter q handles edge (o+q), feature group fk (8 features).
// MODE=0: layer 1 — h = selu(skip*t + agg) into LDS, then fused GEMM-2: T2 = h @ W2 + b2 (MFMA).
// MODE=1: layer 2 — h = selu(skip*t + agg), then out = softmax(h @ Wa + ba).

template <int MODE>
__global__ __launch_bounds__(256) void k_spmm(const __hip_bfloat16* __restrict__ T,
                                              const unsigned* __restrict__ staging4,
                                              const int* __restrict__ rowptr,
                                              const float* __restrict__ skip,
                                              const s8v* __restrict__ Wfb,       // MODE0: Wf2 frags
                                              const float* __restrict__ bias2,   // MODE0: b2
                                              __hip_bfloat16* __restrict__ T2,   // MODE0 out
                                              const float* __restrict__ Wa,      // MODE1
                                              const float* __restrict__ ba,      // MODE1
                                              float* __restrict__ aout) {        // MODE1 out
    __shared__ __align__(16) unsigned srec[MAXB + 16];
    __shared__ int rowoff[17];
    __shared__ __align__(16) __hip_bfloat16 hbuf[(MODE == 0) ? (16 * HB_LD) : 8];
    int b = blockIdx.x;
    int tid = threadIdx.x;

    if (tid < 17) rowoff[tid] = rowptr[b * 17 + tid];
    __syncthreads();
    int cnt = rowoff[16];
    int nv4 = (cnt + 11) >> 2;   // records + 8 pads, in uint4s
    const uint4* sp4 = (const uint4*)(staging4 + (size_t)b * SB);
    for (int i = tid; i < nv4; i += 256) ((uint4*)srec)[i] = sp4[i];
    __syncthreads();

    int wv = tid >> 6, lane = tid & 63;
    int q = lane >> 4;
    int fk = lane & 15;
    const int4* Tv4 = (const int4*)T;   // row = 16 int4 (256 B)

    float sk[8];
    *(float4*)&sk[0] = *(const float4*)(skip + fk * 8);
    *(float4*)&sk[4] = *(const float4*)(skip + fk * 8 + 4);

    float wreg[32];  // MODE1: Wa[8fk+j][4q+c]
    float bav[4];
    if (MODE == 1) {
        #pragma unroll
        for (int j = 0; j < 8; j++)
            *(float4*)&wreg[j * 4] = *(const float4*)(Wa + (size_t)(8 * fk + j) * KC + 4 * q);
        #pragma unroll
        for (int c = 0; c < 4; c++) bav[c] = ba[4 * q + c];
    }

    const float scale = 1.0507009873554805f, alpha = 1.6732632423543772f;

    for (int r = wv; r < 16; r += 4) {
        int g = b * 16 + r;
        int o = rowoff[r], oe = rowoff[r + 1];
        f2v a01 = (f2v){0.f, 0.f}, a23 = (f2v){0.f, 0.f};
        f2v a45 = (f2v){0.f, 0.f}, a67 = (f2v){0.f, 0.f};

        for (; o + 16 <= oe; o += 16) {   // 4 independent 16B gathers in flight
            unsigned c0 = srec[o + q];
            unsigned c1 = srec[o + 4 + q];
            unsigned c2 = srec[o + 8 + q];
            unsigned c3 = srec[o + 12 + q];
            int4 t0 = Tv4[(size_t)(c0 & 0xFFFFu) * 16 + fk];
            int4 t1 = Tv4[(size_t)(c1 & 0xFFFFu) * 16 + fk];
            int4 t2 = Tv4[(size_t)(c2 & 0xFFFFu) * 16 + fk];
            int4 t3 = Tv4[(size_t)(c3 & 0xFFFFu) * 16 + fk];
            float w0 = wof(c0), w1 = wof(c1), w2 = wof(c2), w3 = wof(c3);
            a01 += w0 * up2(t0.x); a23 += w0 * up2(t0.y);
            a45 += w0 * up2(t0.z); a67 += w0 * up2(t0.w);
            a01 += w1 * up2(t1.x); a23 += w1 * up2(t1.y);
            a45 += w1 * up2(t1.z); a67 += w1 * up2(t1.w);
            a01 += w2 * up2(t2.x); a23 += w2 * up2(t2.y);
            a45 += w2 * up2(t2.z); a67 += w2 * up2(t2.w);
            a01 += w3 * up2(t3.x); a23 += w3 * up2(t3.y);
            a45 += w3 * up2(t3.z); a67 += w3 * up2(t3.w);
        }
        for (; o + 8 <= oe; o += 8) {
            unsigned c0 = srec[o + q];
            unsigned c1 = srec[o + 4 + q];
            int4 t0 = Tv4[(size_t)(c0 & 0xFFFFu) * 16 + fk];
            int4 t1 = Tv4[(size_t)(c1 & 0xFFFFu) * 16 + fk];
            float w0 = wof(c0), w1 = wof(c1);
            a01 += w0 * up2(t0.x); a23 += w0 * up2(t0.y);
            a45 += w0 * up2(t0.z); a67 += w0 * up2(t0.w);
            a01 += w1 * up2(t1.x); a23 += w1 * up2(t1.y);
            a45 += w1 * up2(t1.z); a67 += w1 * up2(t1.w);
        }
        for (; o < oe; o += 4) {           // masked tail (pads keep reads safe)
            int i0 = o + q;
            unsigned c0 = srec[i0];
            int4 t0 = Tv4[(size_t)(c0 & 0xFFFFu) * 16 + fk];
            float w0 = (i0 < oe) ? wof(c0) : 0.f;
            a01 += w0 * up2(t0.x); a23 += w0 * up2(t0.y);
            a45 += w0 * up2(t0.z); a67 += w0 * up2(t0.w);
        }

        float acc[8];
        acc[0] = a01.x; acc[1] = a01.y; acc[2] = a23.x; acc[3] = a23.y;
        acc[4] = a45.x; acc[5] = a45.y; acc[6] = a67.x; acc[7] = a67.y;
        #pragma unroll
        for (int j = 0; j < 8; j++) {
            acc[j] += __shfl_xor(acc[j], 16, 64);
            acc[j] += __shfl_xor(acc[j], 32, 64);
        }

        int4 ts = Tv4[(size_t)g * 16 + fk];
        f2v s01 = up2(ts.x), s23 = up2(ts.y), s45 = up2(ts.z), s67 = up2(ts.w);
        float v[8];
        v[0] = sk[0] * s01.x + acc[0]; v[1] = sk[1] * s01.y + acc[1];
        v[2] = sk[2] * s23.x + acc[2]; v[3] = sk[3] * s23.y + acc[3];
        v[4] = sk[4] * s45.x + acc[4]; v[5] = sk[5] * s45.y + acc[5];
        v[6] = sk[6] * s67.x + acc[6]; v[7] = sk[7] * s67.y + acc[7];
        #pragma unroll
        for (int j = 0; j < 8; j++)
            v[j] = scale * (v[j] > 0.f ? v[j] : alpha * (__expf(v[j]) - 1.f));

        if (MODE == 0) {
            // h row -> LDS tile (bf16), consumed by the fused GEMM-2 below
            if (q == 0) {
                union { int4 i4; __hip_bfloat162 h2[4]; } pk;
                #pragma unroll
                for (int j = 0; j < 4; j++)
                    pk.h2[j] = __float22bfloat162_rn(make_float2(v[2 * j], v[2 * j + 1]));
                *(int4*)&hbuf[r * HB_LD + fk * 8] = pk.i4;
            }
        } else {
            float p4[4] = {0.f, 0.f, 0.f, 0.f};
            #pragma unroll
            for (int j = 0; j < 8; j++)
                #pragma unroll
                for (int c = 0; c < 4; c++) p4[c] += v[j] * wreg[j * 4 + c];
            #pragma unroll
            for (int off = 1; off <= 8; off <<= 1)
                #pragma unroll
                for (int c = 0; c < 4; c++) p4[c] += __shfl_xor(p4[c], off, 64);
            #pragma unroll
            for (int c = 0; c < 4; c++) p4[c] += bav[c];
            float m = fmaxf(fmaxf(p4[0], p4[1]), fmaxf(p4[2], p4[3]));
            m = fmaxf(m, __shfl_xor(m, 16, 64));
            m = fmaxf(m, __shfl_xor(m, 32, 64));
            float e0 = __expf(p4[0] - m), e1 = __expf(p4[1] - m);
            float e2 = __expf(p4[2] - m), e3 = __expf(p4[3] - m);
            float s = e0 + e1 + e2 + e3;
            s += __shfl_xor(s, 16, 64);
            s += __shfl_xor(s, 32, 64);
            if (fk < 4) {
                float ev = e0;
                ev = (fk == 1) ? e1 : ev;
                ev = (fk == 2) ? e2 : ev;
                ev = (fk == 3) ? e3 : ev;
                aout[(size_t)g * KC + 4 * q + fk] = ev / s;
            }
        }
    }

    if (MODE == 0) {
        // fused GEMM-2: T2[16x128] = hbuf[16x128] @ W2 + b2.  Wave wv -> n-tiles wv*2, wv*2+1.
        __syncthreads();
        int col = fk;            // lane & 15
        int quad = q;            // lane >> 4
        int nt0 = wv * 2, nt1 = nt0 + 1;
        f4v acc0 = (f4v){0.f, 0.f, 0.f, 0.f};
        f4v acc1 = (f4v){0.f, 0.f, 0.f, 0.f};
        #pragma unroll
        for (int kc = 0; kc < 4; kc++) {
            s8v a = *(const s8v*)&hbuf[col * HB_LD + kc * 32 + quad * 8];  // A[m=col][k]
            s8v b0 = Wfb[(size_t)(kc * 8 + nt0) * 64 + lane];
            s8v b1 = Wfb[(size_t)(kc * 8 + nt1) * 64 + lane];
            acc0 = __builtin_amdgcn_mfma_f32_16x16x32_bf16(a, b0, acc0, 0, 0, 0);
            acc1 = __builtin_amdgcn_mfma_f32_16x16x32_bf16(a, b1, acc1, 0, 0, 0);
        }
        float bb0 = bias2[nt0 * 16 + col];
        float bb1 = bias2[nt1 * 16 + col];
        #pragma unroll
        for (int r4 = 0; r4 < 4; r4++) {
            int grow = b * 16 + quad * 4 + r4;     // C: row = quad*4 + reg, col = lane&15
            __hip_bfloat16* orow = T2 + (size_t)grow * 128;
            orow[nt0 * 16 + col] = __float2bfloat16(acc0[r4] + bb0);
            orow[nt1 * 16 + col] = __float2bfloat16(acc1[r4] + bb1);
        }
    }
}

// ---------------- launch ----------------

extern "C" void kernel_launch(void* const* d_in, const int* in_sizes, int n_in,
                              void* d_out, int out_size, void* d_ws, size_t ws_size,
                              hipStream_t stream) {
    const float* x     = (const float*)d_in[0];
    const int*   eidx  = (const int*)d_in[1];
    const float* ew    = (const float*)d_in[2];
    const float* W1    = (const float*)d_in[3];
    const float* b1    = (const float*)d_in[4];
    const float* skip1 = (const float*)d_in[5];
    const float* W2    = (const float*)d_in[6];
    const float* b2    = (const float*)d_in[7];
    const float* skip2 = (const float*)d_in[8];
    const float* Wa    = (const float*)d_in[9];
    const float* ba    = (const float*)d_in[10];
    float* out = (float*)d_out;

    const int* dst = eidx;
    const int* src = eidx + NE;

    char* ws = (char*)d_ws;
    size_t off = 0;
    __hip_bfloat16* T  = (__hip_bfloat16*)(ws + off); off += (size_t)NN * DD * 2;        // 12.8 MB
    __hip_bfloat16* T2 = (__hip_bfloat16*)(ws + off); off += (size_t)NN * DD * 2;        // 12.8 MB
    int2* staging2 = (int2*)(ws + off);               off += (size_t)NCHUNK * CHUNK * 8; // 12.83 MB
    unsigned* staging4 = (unsigned*)(ws + off);       off += (size_t)NB * SB * 4;        // 9.8 MB
    unsigned short* offs = (unsigned short*)(ws + off); off += (size_t)NCHUNK * NBP * 2; // 1.63 MB
    int* rowptr = (int*)(ws + off);                   off += (size_t)NB * 17 * 4;        // 212 KB
    s8v* Wf1 = (s8v*)(ws + off);                      off += 2048 * 16;                  // 32 KB
    s8v* Wf2 = (s8v*)(ws + off);                      off += 2048 * 16;                  // 32 KB

    // K1: binsort || wprep(W1) || wprep(W2)
    k_binprep<<<NCHUNK + 4, BT, 0, stream>>>(dst, src, ew, staging2, offs, W1, W2, Wf1, Wf2);
    // K2: rowsort || gemm layer-1
    k_sortgemm<<<NB + GEMM_BLKS, 256, 0, stream>>>(staging2, offs, staging4, rowptr,
                                                   x, Wf1, b1, T);
    // layer-1 aggregate + fused layer-2 GEMM  (T -> T2)
    k_spmm<0><<<NB, 256, 0, stream>>>(T, staging4, rowptr, skip1,
                                      Wf2, b2, T2, nullptr, nullptr, nullptr);
    // layer-2 aggregate + assignment  (T2 -> out)
    k_spmm<1><<<NB, 256, 0, stream>>>(T2, staging4, rowptr, skip2,
                                      nullptr, nullptr, nullptr, Wa, ba, out);
}